// Round 6
// baseline (5800.154 us; speedup 1.0000x reference)
//
#include <hip/hip_runtime.h>
#include <hip/hip_cooperative_groups.h>

namespace cg = cooperative_groups;

typedef __attribute__((ext_vector_type(8))) short short8;
typedef __attribute__((ext_vector_type(4))) float f32x4;

static constexpr int B = 256, T = 250, Z = 128, H = 256, D = 512, KMIX = 20, P = 123;
static constexpr int PARAMS_N = B * T * P;
static constexpr int OUT_ZM = PARAMS_N;
static constexpr int OUT_ZL = PARAMS_N + B * Z;

#define DEVI static __device__ __forceinline__

DEVI unsigned short f2bf(float f) {
    unsigned int u = __float_as_uint(f);
    u += 0x7fffu + ((u >> 16) & 1u);
    return (unsigned short)(u >> 16);
}
DEVI float bf2f(unsigned short s) { return __uint_as_float(((unsigned int)s) << 16); }
DEVI float sigm(float x) { return 1.0f / (1.0f + __expf(-x)); }
DEVI float tanh_(float x) {
    x = fminf(fmaxf(x, -15.0f), 15.0f);
    float e = __expf(2.0f * x);
    return (e - 1.0f) / (e + 1.0f);
}

// ---------------- zero-init (ws is poisoned 0xAA every replay) ----------------
__global__ void k_zero(unsigned short* h1, unsigned short* h2,
                       unsigned short* h1l, unsigned short* h2l,
                       unsigned* flags, unsigned* reg_cnt) {
    int i = blockIdx.x * 256 + threadIdx.x;  // 65536 = B*H
    h1[i] = 0; h2[i] = 0; h1l[i] = 0; h2l[i] = 0;
    if (i < 48 * 1024) flags[i] = 0;  // 48 groups x 32 blocks x 32 uints (128B spacing)
    if (i < 256) reg_cnt[i] = 0;      // 8 XCDs x 32 uints (128B spacing)
}

// ---------------- weight packing ----------------
// Wh [K=HID][4*HID] fp32 -> hi/lo [4*HID][HID] bf16, rows packed n = 4*d + g
template <int HID>
__global__ void k_pack_whT(const float* __restrict__ Wh, unsigned short* __restrict__ ohi,
                           unsigned short* __restrict__ olo) {
    constexpr int N4 = 4 * HID;
    __shared__ float tile[32][33];
    int c0 = blockIdx.x * 32, k0 = blockIdx.y * 32;
    int tx = threadIdx.x, ty = threadIdx.y;
#pragma unroll
    for (int ii = 0; ii < 4; ii++)
        tile[ty + 8 * ii][tx] = Wh[(size_t)(k0 + ty + 8 * ii) * N4 + c0 + tx];
    __syncthreads();
#pragma unroll
    for (int ii = 0; ii < 4; ii++) {
        int j = ty + 8 * ii;
        int c = c0 + j;
        int g = c / HID, d = c % HID;
        float w = tile[tx][j];
        unsigned short hi = f2bf(w);
        unsigned short lo = f2bf(w - bf2f(hi));
        size_t o = (size_t)(4 * d + g) * HID + k0 + tx;
        ohi[o] = hi;
        olo[o] = lo;
    }
}

// mix_W [512][123] fp32 -> [128][512] bf16 (zero padded cols >=123)
__global__ void k_pack_mix(const float* __restrict__ W, unsigned short* __restrict__ out) {
    int idx = blockIdx.x * 256 + threadIdx.x;  // 128*512
    int n = idx >> 9, k = idx & 511;
    out[idx] = (n < P) ? f2bf(W[(size_t)k * P + n]) : (unsigned short)0;
}

// fp32 column permutation into packed gate order
__global__ void k_pack_cols(const float* __restrict__ in, float* __restrict__ out, int HID, int N4) {
    int idx = blockIdx.x * 256 + threadIdx.x;
    int row = idx / N4, n = idx % N4;
    out[idx] = in[(size_t)row * N4 + (n & 3) * HID + (n >> 2)];
}

// ---------------- cooperative persistent kernel ----------------
struct CoopArgs {
    const float* data;
    const float* eps;
    const unsigned short *whf_hi, *whf_lo, *whb_hi, *whb_lo, *whd_hi, *whd_lo;
    const float *wxp_ef, *wxp_eb, *wxp_dec, *bp_ef, *bp_eb;
    const float *eoW, *eob, *iW, *ib, *dWx, *db;
    unsigned short *hf_hi, *hf_lo, *hb_hi, *hb_lo;  // [2][B][H] ping-pong
    float* c32_d;
    unsigned short* hs_hi;   // [T+1][B][D] ring
    unsigned short* hlo_pp;  // [2][B][D] ping-pong
    float *zbuf, *zg;
    float* out;
    unsigned* flags;    // [48 groups][32 blocks][32 uints] arrival stamps, 128B apart
    unsigned* reg_cnt;  // [8 XCDs][32 uints] dynamic placement registration
};

// Split-phase group barrier (r5 post-mortem: per-step time is INVARIANT to
// data/weight location => the serial {compute -> flag -> IC round trip ->
// detect} chain IS the bottleneck. Two levers here:)
// 1) arrive/wait are SPLIT so the caller can overlap the flag round trip with
//    the other stream's compute (see run_encoder/run_decoder schedule).
// 2) LOCAL flags live in the XCD's L2, not IC: arrival = plain write-through
//    store (r1-proven to reach L2); poll = atomic RMW fetch_add(0) at
//    workgroup scope — RMWs execute at L2, never in L1, so no r1 staleness
//    and no r3 per-poll buffer_inv. 64-spin escape to agent loads bounds any
//    semantic surprise at ~13ms total instead of a hang.
// Data visibility unchanged from r2-proven: h stores drained by the vmcnt(0)
// at garrive's __syncthreads BEFORE the flag store; consumer does one
// `buffer_inv sc0` (L1-only) after the wait; fresh h is in the same L2.
// Fallback (non-local placement): agent-scope flags + agent acquire fence —
// the r2-proven path, same split schedule.
template <bool LOCAL>
DEVI void garrive(unsigned* flags, int grp, int myblk, unsigned stamp) {
    __syncthreads();  // drains all waves' h stores (vmcnt 0) before the flag
    if (threadIdx.x == 0) {
        if constexpr (LOCAL)
            __hip_atomic_store(flags + (size_t)grp * 1024 + myblk * 32, stamp,
                               __ATOMIC_RELAXED, __HIP_MEMORY_SCOPE_WORKGROUP);
        else
            __hip_atomic_store(flags + (size_t)grp * 1024 + myblk * 32, stamp,
                               __ATOMIC_RELAXED, __HIP_MEMORY_SCOPE_AGENT);
    }
}

template <bool LOCAL>
DEVI void gwait(unsigned* flags, int grp, int nblk, unsigned stamp) {
    int tid = threadIdx.x;
    unsigned* gf = flags + (size_t)grp * 1024;
    if (tid < 64) {
        int spins = 0;
        for (;;) {
            unsigned v = stamp;
            if (tid < nblk) {
                if (LOCAL && spins < 64)
                    v = __hip_atomic_fetch_add(gf + tid * 32, 0u, __ATOMIC_RELAXED,
                                               __HIP_MEMORY_SCOPE_WORKGROUP);
                else
                    v = __hip_atomic_load(gf + tid * 32, __ATOMIC_RELAXED,
                                          __HIP_MEMORY_SCOPE_AGENT);
            }
            if (__all(v >= stamp)) break;
            spins++;
            __builtin_amdgcn_s_sleep(1);
        }
        if (!LOCAL && tid == 0)
            __builtin_amdgcn_fence(__ATOMIC_ACQUIRE, "agent");
    }
    __syncthreads();
    if constexpr (LOCAL)
        asm volatile("buffer_inv sc0" ::: "memory");  // L1 inv; fresh h is in this L2
}

// quad-shuffle gate gather + pointwise update; c lives in a register (quad-redundant)
DEVI float lstm_quad(float v, int g, float& c) {
    float s1 = __shfl_xor(v, 1, 64);
    float s2 = __shfl_xor(v, 2, 64);
    float s3 = __shfl_xor(v, 3, 64);
    float gi, gf, gg, go;
    if (g == 0)      { gi = v;  gf = s1; gg = s2; go = s3; }
    else if (g == 1) { gi = s1; gf = v;  gg = s3; go = s2; }
    else if (g == 2) { gi = s2; gf = s3; gg = v;  go = s1; }
    else             { gi = s3; gf = s2; gg = s1; go = v;  }
    float cnew = sigm(gf) * c + sigm(gi) * tanh_(gg);
    c = cnew;
    return sigm(go) * tanh_(cnew);
}

// packed 4B stores of (hi_d, hi_{d+1}) and (lo_d, lo_{d+1}).
// LOCAL: plain stores -> shared XCD L2 (r1/r2-proven). Fallback: agent-scope.
template <bool LOCAL>
DEVI void store_h_pair(float hnew, int r, unsigned short* __restrict__ hnh,
                       unsigned short* __restrict__ hnl, size_t o_even) {
    unsigned short hi = f2bf(hnew);
    float lo = hnew - bf2f(hi);
    float hp = __shfl_xor(hnew, 4, 64);   // partner lane: d ^ 1, same gate
    unsigned short hip = f2bf(hp);
    float lop = hp - bf2f(hip);
    if ((r & 7) == 0) {
        unsigned pk = (unsigned)hi | ((unsigned)hip << 16);
        if constexpr (LOCAL)
            *(unsigned*)(hnh + o_even) = pk;
        else
            __hip_atomic_store((unsigned*)(hnh + o_even), pk, __ATOMIC_RELAXED, __HIP_MEMORY_SCOPE_AGENT);
    } else if ((r & 7) == 1) {
        unsigned pk = (unsigned)f2bf(lo) | ((unsigned)f2bf(lop) << 16);
        if constexpr (LOCAL)
            *(unsigned*)(hnl + o_even) = pk;
        else
            __hip_atomic_store((unsigned*)(hnl + o_even), pk, __ATOMIC_RELAXED, __HIP_MEMORY_SCOPE_AGENT);
    }
}

// TWO-STREAM interleave: batch rows are independent recurrences; stream 0 =
// rows m0..m0+15 (old acc0), stream 1 = rows m0+16..m0+31 (old acc1). Schedule
//   compute S0(t); arrive(S0,t+1); wait(S1,t); compute S1(t); arrive(S1,t+1);
//   wait(S0,t+1);
// separates every wait from its arrive by one stream-compute, hiding the flag
// round trip. Per-acc accumulation chains are bitwise identical to r2.
// Weights stay in LDS (r5 infra) so both streams reuse one copy (no 2x L2
// weight traffic) and are immune to the per-wait L1 invalidate.

template <bool LOCAL>
DEVI void run_encoder(const CoopArgs& a, float (*smx)[160], char* wraw, int dir, int mb, int nb) {
    int tid = threadIdx.x, w = tid >> 6, lane = tid & 63, q = lane >> 4, r = lane & 15;
    int m0 = mb * 32;
    const unsigned short* __restrict__ whi = dir ? a.whb_hi : a.whf_hi;
    const unsigned short* __restrict__ wlo = dir ? a.whb_lo : a.whf_lo;
    const float* __restrict__ wxp = dir ? a.wxp_eb : a.wxp_ef;
    const float* __restrict__ bp = dir ? a.bp_eb : a.bp_ef;
    unsigned short* __restrict__ hhi = dir ? a.hb_hi : a.hf_hi;
    unsigned short* __restrict__ hlo = dir ? a.hb_lo : a.hf_lo;
    int gbase = (dir * 8 + mb) * 2;  // flag groups [0,32): stream s -> gbase+s
    int c0 = nb * 64;

    int c = c0 + w * 16 + r;
    int g = r & 3, d = c >> 2;
    size_t d_even = (size_t)(d & ~1);

    // stage weight slice into LDS (hi @0, lo @+65536), swizzled (r5-proven)
#pragma unroll
    for (int it = 0; it < 8; it++) {
        int m = it * 256 + tid;
        int row = m >> 5, ch = m & 31;
        int dst = row * 512 + ((ch * 16) ^ ((row & 7) << 4));
        *(short8*)(wraw + dst) = *(const short8*)(whi + (size_t)(c0 + row) * H + ch * 8);
        *(short8*)(wraw + 65536 + dst) = *(const short8*)(wlo + (size_t)(c0 + row) * H + ch * 8);
    }

    float wx0 = wxp[0 * 1024 + c], wx1 = wxp[1 * 1024 + c], wx2 = wxp[2 * 1024 + c];
    float wx3 = wxp[3 * 1024 + c], wx4 = wxp[4 * 1024 + c];
    float bias = bp[c];
    float creg[2][4];
#pragma unroll
    for (int s = 0; s < 2; s++)
#pragma unroll
        for (int rr = 0; rr < 4; rr++) creg[s][rr] = 0.f;

    // stage x(t=0) into LDS buf 0
    {
        int tt0 = dir ? 250 : 1;
        if (tid < 32) {
            const float* p = a.data + (size_t)(m0 + tid) * (5 * (T + 1)) + (size_t)tt0 * 5;
#pragma unroll
            for (int j = 0; j < 5; j++) smx[0][tid * 5 + j] = p[j];
        }
    }
    __syncthreads();

    int crow = w * 16 + r;
    const char* pH = wraw + crow * 512;
    const char* pL = wraw + 65536 + crow * 512;
    int sw = (crow & 7) << 4;
    int q16 = q * 16;

    for (int t = 0; t < T; t++) {
        int pi = t & 1;
        const unsigned short* __restrict__ hph = hhi + (size_t)pi * B * H;
        const unsigned short* __restrict__ hpl = hlo + (size_t)pi * B * H;
        unsigned short* __restrict__ hnh = hhi + (size_t)(1 - pi) * B * H;
        unsigned short* __restrict__ hnl = hlo + (size_t)(1 - pi) * B * H;
        const float* xb = smx[t & 1];

        // ---- stream 0: rows m0..m0+15 ----
        {
            f32x4 acc = {0.f, 0.f, 0.f, 0.f};
#pragma unroll
            for (int ki = 0; ki < 8; ki++) {
                int kb = ki * 32 + q * 8;
                short8 bh = *(const short8*)(pH + ((ki * 64 + q16) ^ sw));
                short8 bl = *(const short8*)(pL + ((ki * 64 + q16) ^ sw));
                short8 ah = *(const short8*)(hph + (size_t)(m0 + r) * H + kb);
                short8 al = *(const short8*)(hpl + (size_t)(m0 + r) * H + kb);
                acc = __builtin_amdgcn_mfma_f32_16x16x32_bf16(ah, bh, acc, 0, 0, 0);
                acc = __builtin_amdgcn_mfma_f32_16x16x32_bf16(al, bh, acc, 0, 0, 0);
                acc = __builtin_amdgcn_mfma_f32_16x16x32_bf16(ah, bl, acc, 0, 0, 0);
            }
            // prefetch x(t+1) into the other LDS buffer (once per t)
            if (t + 1 < T && tid < 32) {
                int ttn = dir ? (249 - t) : (2 + t);
                const float* p = a.data + (size_t)(m0 + tid) * (5 * (T + 1)) + (size_t)ttn * 5;
#pragma unroll
                for (int j = 0; j < 5; j++) smx[(t + 1) & 1][tid * 5 + j] = p[j];
            }
#pragma unroll
            for (int rr = 0; rr < 4; rr++) {
                int brow = q * 4 + rr;
                float v = acc[rr] + bias + xb[brow * 5 + 0] * wx0 + xb[brow * 5 + 1] * wx1 +
                          xb[brow * 5 + 2] * wx2 + xb[brow * 5 + 3] * wx3 + xb[brow * 5 + 4] * wx4;
                float hnew = lstm_quad(v, g, creg[0][rr]);
                store_h_pair<LOCAL>(hnew, r, hnh, hnl, (size_t)(m0 + brow) * H + d_even);
            }
        }
        garrive<LOCAL>(a.flags, gbase + 0, nb, (unsigned)(t + 1));
        gwait<LOCAL>(a.flags, gbase + 1, 16, (unsigned)t);
        // ---- stream 1: rows m0+16..m0+31 ----
        {
            f32x4 acc = {0.f, 0.f, 0.f, 0.f};
#pragma unroll
            for (int ki = 0; ki < 8; ki++) {
                int kb = ki * 32 + q * 8;
                short8 bh = *(const short8*)(pH + ((ki * 64 + q16) ^ sw));
                short8 bl = *(const short8*)(pL + ((ki * 64 + q16) ^ sw));
                short8 ah = *(const short8*)(hph + (size_t)(m0 + 16 + r) * H + kb);
                short8 al = *(const short8*)(hpl + (size_t)(m0 + 16 + r) * H + kb);
                acc = __builtin_amdgcn_mfma_f32_16x16x32_bf16(ah, bh, acc, 0, 0, 0);
                acc = __builtin_amdgcn_mfma_f32_16x16x32_bf16(al, bh, acc, 0, 0, 0);
                acc = __builtin_amdgcn_mfma_f32_16x16x32_bf16(ah, bl, acc, 0, 0, 0);
            }
#pragma unroll
            for (int rr = 0; rr < 4; rr++) {
                int brow = 16 + q * 4 + rr;
                float v = acc[rr] + bias + xb[brow * 5 + 0] * wx0 + xb[brow * 5 + 1] * wx1 +
                          xb[brow * 5 + 2] * wx2 + xb[brow * 5 + 3] * wx3 + xb[brow * 5 + 4] * wx4;
                float hnew = lstm_quad(v, g, creg[1][rr]);
                store_h_pair<LOCAL>(hnew, r, hnh, hnl, (size_t)(m0 + brow) * H + d_even);
            }
        }
        garrive<LOCAL>(a.flags, gbase + 1, nb, (unsigned)(t + 1));
        gwait<LOCAL>(a.flags, gbase + 0, 16, (unsigned)(t + 1));
    }
}

template <bool LOCAL>
DEVI void run_decoder(const CoopArgs& a, float (*smx)[160], char* wraw, int mb, int nb) {
    int tid = threadIdx.x, w = tid >> 6, lane = tid & 63, q = lane >> 4, r = lane & 15;
    int m0 = mb * 32;
    int gbase = 32 + mb * 2;  // flag groups [32,48)
    int c0 = nb * 64;

    int c = c0 + w * 16 + r;
    int g = r & 3, d = c >> 2;
    size_t d_even = (size_t)(d & ~1);

    // stage weight slice into LDS (hi @0, lo @+65536), swizzled (r5-proven)
#pragma unroll
    for (int it = 0; it < 16; it++) {
        int m = it * 256 + tid;
        int row = m >> 6, ch = m & 63;
        int dst = row * 1024 + ((ch * 16) ^ ((row & 7) << 4));
        *(short8*)(wraw + dst) = *(const short8*)(a.whd_hi + (size_t)(c0 + row) * D + ch * 8);
        *(short8*)(wraw + 65536 + dst) = *(const short8*)(a.whd_lo + (size_t)(c0 + row) * D + ch * 8);
    }

    float wx0 = a.wxp_dec[0 * 2048 + c], wx1 = a.wxp_dec[1 * 2048 + c], wx2 = a.wxp_dec[2 * 2048 + c];
    float wx3 = a.wxp_dec[3 * 2048 + c], wx4 = a.wxp_dec[4 * 2048 + c];
    float zgc[2][4], creg[2][4];
#pragma unroll
    for (int s = 0; s < 2; s++)
#pragma unroll
        for (int rr = 0; rr < 4; rr++) {
            int b = m0 + s * 16 + q * 4 + rr;
            zgc[s][rr] = a.zg[(size_t)b * 2048 + c];
            creg[s][rr] = a.c32_d[(size_t)b * D + d];
        }

    if (tid < 32) {
        const float* p = a.data + (size_t)(m0 + tid) * (5 * (T + 1));
#pragma unroll
        for (int j = 0; j < 5; j++) smx[0][tid * 5 + j] = p[j];
    }
    __syncthreads();

    int crow = w * 16 + r;
    const char* pH = wraw + crow * 1024;
    const char* pL = wraw + 65536 + crow * 1024;
    int sw = (crow & 7) << 4;
    int q16 = q * 16;

    for (int t = 0; t < T; t++) {
        int pi = t & 1;
        const unsigned short* __restrict__ hph = a.hs_hi + (size_t)t * B * D;
        const unsigned short* __restrict__ hpl = a.hlo_pp + (size_t)pi * B * D;
        unsigned short* __restrict__ hnh = a.hs_hi + (size_t)(t + 1) * B * D;
        unsigned short* __restrict__ hnl = a.hlo_pp + (size_t)(1 - pi) * B * D;
        const float* xb = smx[t & 1];

        // ---- stream 0: rows m0..m0+15 ----
        {
            f32x4 acc = {0.f, 0.f, 0.f, 0.f};
#pragma unroll
            for (int ki = 0; ki < 16; ki++) {
                int kb = ki * 32 + q * 8;
                short8 bh = *(const short8*)(pH + ((ki * 64 + q16) ^ sw));
                short8 bl = *(const short8*)(pL + ((ki * 64 + q16) ^ sw));
                short8 ah = *(const short8*)(hph + (size_t)(m0 + r) * D + kb);
                short8 al = *(const short8*)(hpl + (size_t)(m0 + r) * D + kb);
                acc = __builtin_amdgcn_mfma_f32_16x16x32_bf16(ah, bh, acc, 0, 0, 0);
                acc = __builtin_amdgcn_mfma_f32_16x16x32_bf16(al, bh, acc, 0, 0, 0);
                acc = __builtin_amdgcn_mfma_f32_16x16x32_bf16(ah, bl, acc, 0, 0, 0);
            }
            if (t + 1 < T && tid < 32) {
                const float* p = a.data + (size_t)(m0 + tid) * (5 * (T + 1)) + (size_t)(t + 1) * 5;
#pragma unroll
                for (int j = 0; j < 5; j++) smx[(t + 1) & 1][tid * 5 + j] = p[j];
            }
#pragma unroll
            for (int rr = 0; rr < 4; rr++) {
                int brow = q * 4 + rr;
                float v = acc[rr] + zgc[0][rr] + xb[brow * 5 + 0] * wx0 + xb[brow * 5 + 1] * wx1 +
                          xb[brow * 5 + 2] * wx2 + xb[brow * 5 + 3] * wx3 + xb[brow * 5 + 4] * wx4;
                float hnew = lstm_quad(v, g, creg[0][rr]);
                store_h_pair<LOCAL>(hnew, r, hnh, hnl, (size_t)(m0 + brow) * D + d_even);
            }
        }
        garrive<LOCAL>(a.flags, gbase + 0, nb, (unsigned)(t + 1));
        gwait<LOCAL>(a.flags, gbase + 1, 32, (unsigned)t);
        // ---- stream 1: rows m0+16..m0+31 ----
        {
            f32x4 acc = {0.f, 0.f, 0.f, 0.f};
#pragma unroll
            for (int ki = 0; ki < 16; ki++) {
                int kb = ki * 32 + q * 8;
                short8 bh = *(const short8*)(pH + ((ki * 64 + q16) ^ sw));
                short8 bl = *(const short8*)(pL + ((ki * 64 + q16) ^ sw));
                short8 ah = *(const short8*)(hph + (size_t)(m0 + 16 + r) * D + kb);
                short8 al = *(const short8*)(hpl + (size_t)(m0 + 16 + r) * D + kb);
                acc = __builtin_amdgcn_mfma_f32_16x16x32_bf16(ah, bh, acc, 0, 0, 0);
                acc = __builtin_amdgcn_mfma_f32_16x16x32_bf16(al, bh, acc, 0, 0, 0);
                acc = __builtin_amdgcn_mfma_f32_16x16x32_bf16(ah, bl, acc, 0, 0, 0);
            }
#pragma unroll
            for (int rr = 0; rr < 4; rr++) {
                int brow = 16 + q * 4 + rr;
                float v = acc[rr] + zgc[1][rr] + xb[brow * 5 + 0] * wx0 + xb[brow * 5 + 1] * wx1 +
                          xb[brow * 5 + 2] * wx2 + xb[brow * 5 + 3] * wx3 + xb[brow * 5 + 4] * wx4;
                float hnew = lstm_quad(v, g, creg[1][rr]);
                store_h_pair<LOCAL>(hnew, r, hnh, hnl, (size_t)(m0 + brow) * D + d_even);
            }
        }
        garrive<LOCAL>(a.flags, gbase + 1, nb, (unsigned)(t + 1));
        gwait<LOCAL>(a.flags, gbase + 0, 32, (unsigned)(t + 1));
    }
}

DEVI void run_encout(const CoopArgs& a, float* smem) {
    int b = blockIdx.x, tid = threadIdx.x;
    // final encoder h is in ping-pong slot 0 (T=250 even)
    if (tid < 128) {
        smem[tid]       = bf2f(a.hf_hi[(size_t)b * H + tid])       + bf2f(a.hf_lo[(size_t)b * H + tid]);
        smem[tid + 128] = bf2f(a.hf_hi[(size_t)b * H + tid + 128]) + bf2f(a.hf_lo[(size_t)b * H + tid + 128]);
        smem[tid + 256] = bf2f(a.hb_hi[(size_t)b * H + tid])       + bf2f(a.hb_lo[(size_t)b * H + tid]);
        smem[tid + 384] = bf2f(a.hb_hi[(size_t)b * H + tid + 128]) + bf2f(a.hb_lo[(size_t)b * H + tid + 128]);
    }
    __syncthreads();
    if (tid < 128) {
        float mean = a.eob[tid], lv = a.eob[Z + tid];
        for (int k = 0; k < 2 * H; k++) {
            float h = smem[k];
            mean += h * a.eoW[(size_t)k * 2 * Z + tid];
            lv += h * a.eoW[(size_t)k * 2 * Z + Z + tid];
        }
        float z = mean + __expf(0.5f * lv) * a.eps[(size_t)b * Z + tid];
        a.out[OUT_ZM + (size_t)b * Z + tid] = mean;
        a.out[OUT_ZL + (size_t)b * Z + tid] = lv;
        a.zbuf[(size_t)b * Z + tid] = z;
    }
    __syncthreads();
}

DEVI void run_init_zg(const CoopArgs& a, float* smem) {
    int bid = blockIdx.x, tid = threadIdx.x;
    if (bid < 64) {
        int cc = (bid & 3) * 256 + tid;
        int b0 = (bid >> 2) * 16;
        for (int i = tid; i < 16 * Z; i += 256)
            smem[i] = a.zbuf[(size_t)(b0 + (i >> 7)) * Z + (i & 127)];
        __syncthreads();
        float acc[16];
        float bias = a.ib[cc];
#pragma unroll
        for (int bb = 0; bb < 16; bb++) acc[bb] = bias;
        for (int k = 0; k < Z; k++) {
            float wv = a.iW[(size_t)k * 1024 + cc];
#pragma unroll
            for (int bb = 0; bb < 16; bb++) acc[bb] += smem[bb * 128 + k] * wv;
        }
        for (int bb = 0; bb < 16; bb++) {
            float v = tanh_(acc[bb]);
            int b = b0 + bb;
            if (cc < D) {
                unsigned short hi = f2bf(v);
                a.hs_hi[(size_t)b * D + cc] = hi;
                a.hlo_pp[(size_t)b * D + cc] = f2bf(v - bf2f(hi));
            } else {
                a.c32_d[(size_t)b * D + (cc - D)] = v;
            }
        }
    } else if (bid < 192) {
        int bid2 = bid - 64;
        int cc = (bid2 & 7) * 256 + tid;
        int b0 = (bid2 >> 3) * 16;
        for (int i = tid; i < 16 * Z; i += 256)
            smem[i] = a.zbuf[(size_t)(b0 + (i >> 7)) * Z + (i & 127)];
        __syncthreads();
        float acc[16];
        float db_c = a.db[cc];
#pragma unroll
        for (int bb = 0; bb < 16; bb++) acc[bb] = db_c;
        for (int k = 0; k < Z; k++) {
            float wv = a.dWx[(size_t)(5 + k) * 2048 + cc];
#pragma unroll
            for (int bb = 0; bb < 16; bb++) acc[bb] += smem[bb * 128 + k] * wv;
        }
        int n = 4 * (cc & 511) + (cc >> 9);
#pragma unroll
        for (int bb = 0; bb < 16; bb++) a.zg[(size_t)(b0 + bb) * 2048 + n] = acc[bb];
    }
    __syncthreads();
}

__global__ __launch_bounds__(256, 1) void k_coop(CoopArgs a) {
    __shared__ float smem[2048];
    __shared__ float smx[2][160];
    __shared__ int s_info[2];
    __shared__ __align__(16) char wraw[131072];  // weight slice: hi @0, lo @65536

    // --- dynamic XCD registration: groups become XCD-local BY CONSTRUCTION ---
    if (threadIdx.x == 0) {
        unsigned x;
        asm volatile("s_getreg_b32 %0, hwreg(HW_REG_XCC_ID)" : "=s"(x));
        x &= 7;
        s_info[0] = (int)x;
        s_info[1] = (int)atomicAdd(a.reg_cnt + x * 32, 1u);  // device-scope
    }
    __syncthreads();
    int xcd = s_info[0], slot = s_info[1];
    cg::this_grid().sync();
    // grid-uniform verdict: every XCD must host exactly 32 of the 256 blocks
    bool local = (slot < 32);
#pragma unroll
    for (int i = 0; i < 8; i++) local = local && (a.reg_cnt[i * 32] == 32u);

    if (local) {
        // encoder: 2 groups per XCD (16 blocks each): dir = upper/lower slot half
        run_encoder<true>(a, smx, wraw, slot >> 4, xcd, slot & 15);
    } else {
        int bid = blockIdx.x;
        run_encoder<false>(a, smx, wraw, bid >> 7, (bid >> 4) & 7, bid & 15);
    }
    cg::this_grid().sync();
    run_encout(a, smem);
    cg::this_grid().sync();
    run_init_zg(a, smem);
    cg::this_grid().sync();
    if (local) {
        // decoder: 1 group per XCD (all 32 blocks)
        run_decoder<true>(a, smx, wraw, xcd, slot);
    } else {
        run_decoder<false>(a, smx, wraw, blockIdx.x >> 5, blockIdx.x & 31);
    }
}

// ---------------- mix GEMM ----------------
__global__ __launch_bounds__(256) void k_mix(const unsigned short* __restrict__ hs,
                                             const unsigned short* __restrict__ mixwt,
                                             const float* __restrict__ mb, float* __restrict__ dout) {
    int tid = threadIdx.x, wave = tid >> 6, lane = tid & 63, q = lane >> 4, r = lane & 15;
    int m0 = blockIdx.y * 64 + (wave >> 1) * 32;
    int n0 = blockIdx.x * 64 + (wave & 1) * 32;
    const unsigned short* A = hs + (size_t)B * D;  // ring slots 1..T
    f32x4 acc[2][2];
#pragma unroll
    for (int mi = 0; mi < 2; mi++)
#pragma unroll
        for (int ni = 0; ni < 2; ni++) acc[mi][ni] = {0.f, 0.f, 0.f, 0.f};
#pragma unroll 4
    for (int kk = 0; kk < D; kk += 32) {
        int kb = kk + q * 8;
        short8 a0 = *(const short8*)(A + (size_t)(m0 + r) * D + kb);
        short8 a1 = *(const short8*)(A + (size_t)(m0 + 16 + r) * D + kb);
        short8 b0 = *(const short8*)(mixwt + (size_t)(n0 + r) * D + kb);
        short8 b1 = *(const short8*)(mixwt + (size_t)(n0 + 16 + r) * D + kb);
        acc[0][0] = __builtin_amdgcn_mfma_f32_16x16x32_bf16(a0, b0, acc[0][0], 0, 0, 0);
        acc[0][1] = __builtin_amdgcn_mfma_f32_16x16x32_bf16(a0, b1, acc[0][1], 0, 0, 0);
        acc[1][0] = __builtin_amdgcn_mfma_f32_16x16x32_bf16(a1, b0, acc[1][0], 0, 0, 0);
        acc[1][1] = __builtin_amdgcn_mfma_f32_16x16x32_bf16(a1, b1, acc[1][1], 0, 0, 0);
    }
#pragma unroll
    for (int ni = 0; ni < 2; ni++) {
        int ncol = n0 + ni * 16 + r;
        if (ncol < P) {
            float bias = mb[ncol];
#pragma unroll
            for (int mi = 0; mi < 2; mi++) {
#pragma unroll
                for (int rr = 0; rr < 4; rr++) {
                    int m = m0 + mi * 16 + q * 4 + rr;
                    int b = m & 255, t = m >> 8;
                    dout[((size_t)b * T + t) * P + ncol] = acc[mi][ni][rr] + bias;
                }
            }
        }
    }
}

// ---------------- per-row epilogue ----------------
__global__ void k_post(float* __restrict__ dout) {
    __shared__ float row[P];
    int rid = blockIdx.x;
    int tid = threadIdx.x;
    float* base = dout + (size_t)rid * P;
    float v = 0.f;
    if (tid < P) { v = base[tid]; row[tid] = v; }
    __syncthreads();
    if (tid < P) {
        float o;
        if (tid < KMIX) {
            float mx = row[0];
            for (int i = 1; i < KMIX; i++) mx = fmaxf(mx, row[i]);
            float sm = 0.f;
            for (int i = 0; i < KMIX; i++) sm += __expf(row[i] - mx);
            o = __expf(v - mx) / sm;
        } else if (tid < 3 * KMIX) o = v;
        else if (tid < 5 * KMIX) o = __expf(v);
        else if (tid < 6 * KMIX) o = tanh_(v);
        else o = v;
        base[tid] = o;
    }
}

extern "C" void kernel_launch(void* const* d_in, const int* in_sizes, int n_in,
                              void* d_out, int out_size, void* d_ws, size_t ws_size,
                              hipStream_t stream) {
    const float* data = (const float*)d_in[0];
    const float* eps  = (const float*)d_in[1];
    const float* eWxf = (const float*)d_in[2];
    const float* eWhf = (const float*)d_in[3];
    const float* ebf  = (const float*)d_in[4];
    const float* eWxb = (const float*)d_in[5];
    const float* eWhb = (const float*)d_in[6];
    const float* ebb  = (const float*)d_in[7];
    const float* eoW  = (const float*)d_in[8];
    const float* eob  = (const float*)d_in[9];
    const float* iW   = (const float*)d_in[10];
    const float* ib   = (const float*)d_in[11];
    const float* dWx  = (const float*)d_in[12];
    const float* dWh  = (const float*)d_in[13];
    const float* db   = (const float*)d_in[14];
    const float* mW   = (const float*)d_in[15];
    const float* mb   = (const float*)d_in[16];
    float* out = (float*)d_out;

    char* base = (char*)d_ws;
    size_t off = 0;
    auto alloc = [&](size_t bytes) -> char* {
        off = (off + 255) & ~(size_t)255;
        char* p = base + off;
        off += bytes;
        return p;
    };
    unsigned short* whd_hi = (unsigned short*)alloc((size_t)2048 * 512 * 2);
    unsigned short* whd_lo = (unsigned short*)alloc((size_t)2048 * 512 * 2);
    unsigned short* whf_hi = (unsigned short*)alloc((size_t)1024 * 256 * 2);
    unsigned short* whf_lo = (unsigned short*)alloc((size_t)1024 * 256 * 2);
    unsigned short* whb_hi = (unsigned short*)alloc((size_t)1024 * 256 * 2);
    unsigned short* whb_lo = (unsigned short*)alloc((size_t)1024 * 256 * 2);
    unsigned short* mixwt  = (unsigned short*)alloc((size_t)128 * 512 * 2);
    float* wxp_dec = (float*)alloc((size_t)5 * 2048 * 4);
    float* wxp_ef  = (float*)alloc((size_t)5 * 1024 * 4);
    float* wxp_eb  = (float*)alloc((size_t)5 * 1024 * 4);
    float* bp_ef   = (float*)alloc((size_t)1024 * 4);
    float* bp_eb   = (float*)alloc((size_t)1024 * 4);
    unsigned short* hf_hi = (unsigned short*)alloc((size_t)2 * B * H * 2);
    unsigned short* hf_lo = (unsigned short*)alloc((size_t)2 * B * H * 2);
    unsigned short* hb_hi = (unsigned short*)alloc((size_t)2 * B * H * 2);
    unsigned short* hb_lo = (unsigned short*)alloc((size_t)2 * B * H * 2);
    float* c32_d  = (float*)alloc((size_t)B * D * 4);
    unsigned short* hs_hi = (unsigned short*)alloc((size_t)(T + 1) * B * D * 2);
    unsigned short* hlo_pp = (unsigned short*)alloc((size_t)2 * B * D * 2);
    float* zbuf = (float*)alloc((size_t)B * Z * 4);
    float* zg   = (float*)alloc((size_t)B * 2048 * 4);
    unsigned* flags = (unsigned*)alloc((size_t)48 * 1024 * 4);
    unsigned* reg_cnt = (unsigned*)alloc((size_t)256 * 4);
    (void)ws_size; (void)in_sizes; (void)n_in; (void)out_size;

    k_zero<<<256, 256, 0, stream>>>(hf_hi, hb_hi, hf_lo, hb_lo, flags, reg_cnt);
    k_pack_whT<512><<<dim3(64, 16), dim3(32, 8), 0, stream>>>(dWh, whd_hi, whd_lo);
    k_pack_whT<256><<<dim3(32, 8), dim3(32, 8), 0, stream>>>(eWhf, whf_hi, whf_lo);
    k_pack_whT<256><<<dim3(32, 8), dim3(32, 8), 0, stream>>>(eWhb, whb_hi, whb_lo);
    k_pack_mix<<<256, 256, 0, stream>>>(mW, mixwt);
    k_pack_cols<<<40, 256, 0, stream>>>(dWx, wxp_dec, 512, 2048);
    k_pack_cols<<<20, 256, 0, stream>>>(eWxf, wxp_ef, 256, 1024);
    k_pack_cols<<<20, 256, 0, stream>>>(eWxb, wxp_eb, 256, 1024);
    k_pack_cols<<<4, 256, 0, stream>>>(ebf, bp_ef, 256, 1024);
    k_pack_cols<<<4, 256, 0, stream>>>(ebb, bp_eb, 256, 1024);

    CoopArgs ca;
    ca.data = data; ca.eps = eps;
    ca.whf_hi = whf_hi; ca.whf_lo = whf_lo; ca.whb_hi = whb_hi; ca.whb_lo = whb_lo;
    ca.whd_hi = whd_hi; ca.whd_lo = whd_lo;
    ca.wxp_ef = wxp_ef; ca.wxp_eb = wxp_eb; ca.wxp_dec = wxp_dec;
    ca.bp_ef = bp_ef; ca.bp_eb = bp_eb;
    ca.eoW = eoW; ca.eob = eob; ca.iW = iW; ca.ib = ib; ca.dWx = dWx; ca.db = db;
    ca.hf_hi = hf_hi; ca.hf_lo = hf_lo; ca.hb_hi = hb_hi; ca.hb_lo = hb_lo;
    ca.c32_d = c32_d;
    ca.hs_hi = hs_hi; ca.hlo_pp = hlo_pp;
    ca.zbuf = zbuf; ca.zg = zg; ca.out = out;
    ca.flags = flags; ca.reg_cnt = reg_cnt;

    void* kp[] = { &ca };
    hipLaunchCooperativeKernel((void*)k_coop, dim3(256), dim3(256), kp, 0, stream);

    k_mix<<<dim3(2, 1000), 256, 0, stream>>>(hs_hi, mixwt, mb, out);
    k_post<<<64000, 128, 0, stream>>>(out);
}

// Round 7
// 5291.394 us; speedup vs baseline: 1.0961x; 1.0961x over previous
//
#include <hip/hip_runtime.h>
#include <hip/hip_cooperative_groups.h>

namespace cg = cooperative_groups;

typedef __attribute__((ext_vector_type(8))) short short8;
typedef __attribute__((ext_vector_type(4))) float f32x4;

static constexpr int B = 256, T = 250, Z = 128, H = 256, D = 512, KMIX = 20, P = 123;
static constexpr int PARAMS_N = B * T * P;
static constexpr int OUT_ZM = PARAMS_N;
static constexpr int OUT_ZL = PARAMS_N + B * Z;

#define DEVI static __device__ __forceinline__

DEVI unsigned short f2bf(float f) {
    unsigned int u = __float_as_uint(f);
    u += 0x7fffu + ((u >> 16) & 1u);
    return (unsigned short)(u >> 16);
}
DEVI float bf2f(unsigned short s) { return __uint_as_float(((unsigned int)s) << 16); }
DEVI float sigm(float x) { return 1.0f / (1.0f + __expf(-x)); }
DEVI float tanh_(float x) {
    x = fminf(fmaxf(x, -15.0f), 15.0f);
    float e = __expf(2.0f * x);
    return (e - 1.0f) / (e + 1.0f);
}

// L2-executed atomic fetch_add (CDNA: global atomics execute in the XCD's L2;
// no sc1 => no IC escalation). sc0 = return old value. Two L2 atomics on the
// same address share one serialization point -> no staleness possible (unlike
// sc0 loads (r1) or workgroup-scope RMWs (r6), both of which were satisfied
// CU-side and never saw peer flags).
DEVI unsigned l2_fetch_add(unsigned* p, unsigned val) {
    unsigned old;
    asm volatile("global_atomic_add %0, %1, %2, off sc0\n\ts_waitcnt vmcnt(0)"
                 : "=v"(old)
                 : "v"(p), "v"(val)
                 : "memory");
    return old;
}

// ---------------- zero-init (ws is poisoned 0xAA every replay) ----------------
__global__ void k_zero(unsigned short* h1, unsigned short* h2,
                       unsigned short* h1l, unsigned short* h2l,
                       unsigned* flags, unsigned* go, unsigned* ctrs, unsigned* reg_cnt) {
    int i = blockIdx.x * 256 + threadIdx.x;  // 65536 = B*H
    h1[i] = 0; h2[i] = 0; h1l[i] = 0; h2l[i] = 0;
    if (i < 24 * 1024) flags[i] = 0;  // 24 groups x 32 blocks x 32 uints (fallback)
    if (i < 24 * 32) go[i] = 0;       // 24 groups x 1 line (fallback)
    if (i < 24 * 32) ctrs[i] = 0;     // 24 groups x 1 line (LOCAL L2 counters)
    if (i < 256) reg_cnt[i] = 0;      // 8 XCDs x 32 uints
}

// ---------------- weight packing ----------------
// Wh [K=HID][4*HID] fp32 -> hi/lo [4*HID][HID] bf16, rows packed n = 4*d + g
template <int HID>
__global__ void k_pack_whT(const float* __restrict__ Wh, unsigned short* __restrict__ ohi,
                           unsigned short* __restrict__ olo) {
    constexpr int N4 = 4 * HID;
    __shared__ float tile[32][33];
    int c0 = blockIdx.x * 32, k0 = blockIdx.y * 32;
    int tx = threadIdx.x, ty = threadIdx.y;
#pragma unroll
    for (int ii = 0; ii < 4; ii++)
        tile[ty + 8 * ii][tx] = Wh[(size_t)(k0 + ty + 8 * ii) * N4 + c0 + tx];
    __syncthreads();
#pragma unroll
    for (int ii = 0; ii < 4; ii++) {
        int j = ty + 8 * ii;
        int c = c0 + j;
        int g = c / HID, d = c % HID;
        float w = tile[tx][j];
        unsigned short hi = f2bf(w);
        unsigned short lo = f2bf(w - bf2f(hi));
        size_t o = (size_t)(4 * d + g) * HID + k0 + tx;
        ohi[o] = hi;
        olo[o] = lo;
    }
}

// mix_W [512][123] fp32 -> [128][512] bf16 (zero padded cols >=123)
__global__ void k_pack_mix(const float* __restrict__ W, unsigned short* __restrict__ out) {
    int idx = blockIdx.x * 256 + threadIdx.x;  // 128*512
    int n = idx >> 9, k = idx & 511;
    out[idx] = (n < P) ? f2bf(W[(size_t)k * P + n]) : (unsigned short)0;
}

// fp32 column permutation into packed gate order
__global__ void k_pack_cols(const float* __restrict__ in, float* __restrict__ out, int HID, int N4) {
    int idx = blockIdx.x * 256 + threadIdx.x;
    int row = idx / N4, n = idx % N4;
    out[idx] = in[(size_t)row * N4 + (n & 3) * HID + (n >> 2)];
}

// ---------------- cooperative persistent kernel ----------------
struct CoopArgs {
    const float* data;
    const float* eps;
    const unsigned short *whf_hi, *whf_lo, *whb_hi, *whb_lo, *whd_hi, *whd_lo;
    const float *wxp_ef, *wxp_eb, *wxp_dec, *bp_ef, *bp_eb;
    const float *eoW, *eob, *iW, *ib, *dWx, *db;
    unsigned short *hf_hi, *hf_lo, *hb_hi, *hb_lo;  // [2][B][H] ping-pong
    float* c32_d;
    unsigned short* hs_hi;   // [T+1][B][D] ring
    unsigned short* hlo_pp;  // [2][B][D] ping-pong
    float *zbuf, *zg;
    float* out;
    unsigned* flags;    // [24 groups][32 blocks][32 uints] (fallback arrivals)
    unsigned* go;       // [24 groups][32 uints] (fallback broadcast)
    unsigned* ctrs;     // [24 groups][32 uints] cumulative L2 arrival counters (LOCAL)
    unsigned* reg_cnt;  // [8 XCDs][32 uints] dynamic placement registration
};

// Group barrier.
// LOCAL=true (group == one XCD; r6 post-mortem: barrier cost scales with the
//   NUMBER of barrier ops, each paying a fixed IC round trip — so move the
//   flags' serialization point from IC to the XCD's L2):
//   - cumulative counter, ONE cache line per group.
//   - arrival: L2 atomic fetch_add(1) (after entry __syncthreads has drained
//     all h stores into the SAME L2 — vmcnt(0) per wave before s_barrier).
//   - wait: lane 0 polls L2 atomic fetch_add(0) until ctr >= nblk*stamp.
//     Detect latency = one L2 atomic (~250cy) instead of a 32-line IC gather.
//   - acquire for h data: single `buffer_inv sc0` (L1-only inv; fresh h lives
//     in this L2) — r1/r2/r5-proven position and cost.
// LOCAL=false: grid-uniform agent-scope leader/go barrier — baseline-proven,
//   byte-identical to r2/r5.
template <bool LOCAL>
DEVI void group_barrier(unsigned* flags, unsigned* go, unsigned* ctrs, int grp, int myblk,
                        int nblk, unsigned stamp) {
    __syncthreads();
    int tid = threadIdx.x;
    if constexpr (LOCAL) {
        if (tid == 0) {
            unsigned* cp = ctrs + (size_t)grp * 32;
            unsigned target = (unsigned)nblk * stamp;
            unsigned v = l2_fetch_add(cp, 1u) + 1u;
            while (v < target) {
                __builtin_amdgcn_s_sleep(1);
                v = l2_fetch_add(cp, 0u);
            }
        }
        __syncthreads();
        asm volatile("buffer_inv sc0" ::: "memory");  // acquire: L1 inv; L2 holds fresh h
    } else {
        unsigned* gf = flags + (size_t)grp * 1024;
        if (tid == 0)
            __hip_atomic_store(gf + myblk * 32, stamp, __ATOMIC_RELAXED, __HIP_MEMORY_SCOPE_AGENT);
        if (myblk == 0 && tid < 64) {
            for (;;) {
                unsigned v = (tid < nblk)
                    ? __hip_atomic_load(gf + tid * 32, __ATOMIC_RELAXED, __HIP_MEMORY_SCOPE_AGENT)
                    : stamp;
                if (__all(v >= stamp)) break;
                __builtin_amdgcn_s_sleep(1);
            }
            if (tid == 0)
                __hip_atomic_store(go + grp * 32, stamp, __ATOMIC_RELAXED, __HIP_MEMORY_SCOPE_AGENT);
        }
        if (tid == 0) {
            while (__hip_atomic_load(go + grp * 32, __ATOMIC_RELAXED, __HIP_MEMORY_SCOPE_AGENT) < stamp)
                __builtin_amdgcn_s_sleep(1);
            __builtin_amdgcn_fence(__ATOMIC_ACQUIRE, "agent");
        }
        __syncthreads();
    }
}

// quad-shuffle gate gather + pointwise update; c lives in a register (quad-redundant)
DEVI float lstm_quad(float v, int g, float& c) {
    float s1 = __shfl_xor(v, 1, 64);
    float s2 = __shfl_xor(v, 2, 64);
    float s3 = __shfl_xor(v, 3, 64);
    float gi, gf, gg, go;
    if (g == 0)      { gi = v;  gf = s1; gg = s2; go = s3; }
    else if (g == 1) { gi = s1; gf = v;  gg = s3; go = s2; }
    else if (g == 2) { gi = s2; gf = s3; gg = v;  go = s1; }
    else             { gi = s3; gf = s2; gg = s1; go = v;  }
    float cnew = sigm(gf) * c + sigm(gi) * tanh_(gg);
    c = cnew;
    return sigm(go) * tanh_(cnew);
}

// packed 4B stores of (hi_d, hi_{d+1}) and (lo_d, lo_{d+1}).
// LOCAL: plain stores -> shared XCD L2 (r1/r2-proven). Fallback: agent-scope.
template <bool LOCAL>
DEVI void store_h_pair(float hnew, int r, unsigned short* __restrict__ hnh,
                       unsigned short* __restrict__ hnl, size_t o_even) {
    unsigned short hi = f2bf(hnew);
    float lo = hnew - bf2f(hi);
    float hp = __shfl_xor(hnew, 4, 64);   // partner lane: d ^ 1, same gate
    unsigned short hip = f2bf(hp);
    float lop = hp - bf2f(hip);
    if ((r & 7) == 0) {
        unsigned pk = (unsigned)hi | ((unsigned)hip << 16);
        if constexpr (LOCAL)
            *(unsigned*)(hnh + o_even) = pk;
        else
            __hip_atomic_store((unsigned*)(hnh + o_even), pk, __ATOMIC_RELAXED, __HIP_MEMORY_SCOPE_AGENT);
    } else if ((r & 7) == 1) {
        unsigned pk = (unsigned)f2bf(lo) | ((unsigned)f2bf(lop) << 16);
        if constexpr (LOCAL)
            *(unsigned*)(hnl + o_even) = pk;
        else
            __hip_atomic_store((unsigned*)(hnl + o_even), pk, __ATOMIC_RELAXED, __HIP_MEMORY_SCOPE_AGENT);
    }
}

template <bool LOCAL>
DEVI void run_encoder(const CoopArgs& a, float (*smx)[160], char* wraw, int dir, int mb, int nb) {
    int tid = threadIdx.x, w = tid >> 6, lane = tid & 63, q = lane >> 4, r = lane & 15;
    int m0 = mb * 32;
    const unsigned short* __restrict__ whi = dir ? a.whb_hi : a.whf_hi;
    const unsigned short* __restrict__ wlo = dir ? a.whb_lo : a.whf_lo;
    const float* __restrict__ wxp = dir ? a.wxp_eb : a.wxp_ef;
    const float* __restrict__ bp = dir ? a.bp_eb : a.bp_ef;
    unsigned short* __restrict__ hhi = dir ? a.hb_hi : a.hf_hi;
    unsigned short* __restrict__ hlo = dir ? a.hb_lo : a.hf_lo;
    int grp = dir * 8 + mb;
    int c0 = nb * 64;

    int c = c0 + w * 16 + r;
    int g = r & 3, d = c >> 2;
    size_t d_even = (size_t)(d & ~1);

    // stage weight slice into LDS (hi @0, lo @+65536), swizzled (r5-proven)
#pragma unroll
    for (int it = 0; it < 8; it++) {
        int m = it * 256 + tid;
        int row = m >> 5, ch = m & 31;
        int dst = row * 512 + ((ch * 16) ^ ((row & 7) << 4));
        *(short8*)(wraw + dst) = *(const short8*)(whi + (size_t)(c0 + row) * H + ch * 8);
        *(short8*)(wraw + 65536 + dst) = *(const short8*)(wlo + (size_t)(c0 + row) * H + ch * 8);
    }

    float wx0 = wxp[0 * 1024 + c], wx1 = wxp[1 * 1024 + c], wx2 = wxp[2 * 1024 + c];
    float wx3 = wxp[3 * 1024 + c], wx4 = wxp[4 * 1024 + c];
    float bias = bp[c];
    float creg[2][4];
#pragma unroll
    for (int mi = 0; mi < 2; mi++)
#pragma unroll
        for (int rr = 0; rr < 4; rr++) creg[mi][rr] = 0.f;

    // stage x(t=0) into LDS buf 0
    {
        int tt0 = dir ? 250 : 1;
        if (tid < 32) {
            const float* p = a.data + (size_t)(m0 + tid) * (5 * (T + 1)) + (size_t)tt0 * 5;
#pragma unroll
            for (int j = 0; j < 5; j++) smx[0][tid * 5 + j] = p[j];
        }
    }
    __syncthreads();

    int crow = w * 16 + r;
    const char* pH = wraw + crow * 512;
    const char* pL = wraw + 65536 + crow * 512;
    int sw = (crow & 7) << 4;
    int q16 = q * 16;

    for (int t = 0; t < T; t++) {
        int pi = t & 1;
        const unsigned short* __restrict__ hph = hhi + (size_t)pi * B * H;
        const unsigned short* __restrict__ hpl = hlo + (size_t)pi * B * H;
        f32x4 acc0 = {0.f, 0.f, 0.f, 0.f}, acc1 = {0.f, 0.f, 0.f, 0.f};
#pragma unroll
        for (int ki = 0; ki < 8; ki++) {
            int kb = ki * 32 + q * 8;
            short8 bh = *(const short8*)(pH + ((ki * 64 + q16) ^ sw));
            short8 bl = *(const short8*)(pL + ((ki * 64 + q16) ^ sw));
            short8 a0h = *(const short8*)(hph + (size_t)(m0 + r) * H + kb);
            short8 a1h = *(const short8*)(hph + (size_t)(m0 + 16 + r) * H + kb);
            short8 a0l = *(const short8*)(hpl + (size_t)(m0 + r) * H + kb);
            short8 a1l = *(const short8*)(hpl + (size_t)(m0 + 16 + r) * H + kb);
            acc0 = __builtin_amdgcn_mfma_f32_16x16x32_bf16(a0h, bh, acc0, 0, 0, 0);
            acc1 = __builtin_amdgcn_mfma_f32_16x16x32_bf16(a1h, bh, acc1, 0, 0, 0);
            acc0 = __builtin_amdgcn_mfma_f32_16x16x32_bf16(a0l, bh, acc0, 0, 0, 0);
            acc1 = __builtin_amdgcn_mfma_f32_16x16x32_bf16(a1l, bh, acc1, 0, 0, 0);
            acc0 = __builtin_amdgcn_mfma_f32_16x16x32_bf16(a0h, bl, acc0, 0, 0, 0);
            acc1 = __builtin_amdgcn_mfma_f32_16x16x32_bf16(a1h, bl, acc1, 0, 0, 0);
        }
        // prefetch x(t+1) into the other LDS buffer (overlaps epilogue)
        if (t + 1 < T && tid < 32) {
            int ttn = dir ? (249 - t) : (2 + t);
            const float* p = a.data + (size_t)(m0 + tid) * (5 * (T + 1)) + (size_t)ttn * 5;
#pragma unroll
            for (int j = 0; j < 5; j++) smx[(t + 1) & 1][tid * 5 + j] = p[j];
        }
        unsigned short* __restrict__ hnh = hhi + (size_t)(1 - pi) * B * H;
        unsigned short* __restrict__ hnl = hlo + (size_t)(1 - pi) * B * H;
        const float* xb = smx[t & 1];
#pragma unroll
        for (int mi = 0; mi < 2; mi++) {
            f32x4 acc = mi ? acc1 : acc0;
#pragma unroll
            for (int rr = 0; rr < 4; rr++) {
                int brow = mi * 16 + q * 4 + rr;
                float v = acc[rr] + bias + xb[brow * 5 + 0] * wx0 + xb[brow * 5 + 1] * wx1 +
                          xb[brow * 5 + 2] * wx2 + xb[brow * 5 + 3] * wx3 + xb[brow * 5 + 4] * wx4;
                float hnew = lstm_quad(v, g, creg[mi][rr]);
                store_h_pair<LOCAL>(hnew, r, hnh, hnl, (size_t)(m0 + brow) * H + d_even);
            }
        }
        group_barrier<LOCAL>(a.flags, a.go, a.ctrs, grp, nb, 16, (unsigned)(t + 1));
    }
}

template <bool LOCAL>
DEVI void run_decoder(const CoopArgs& a, float (*smx)[160], char* wraw, int mb, int nb) {
    int tid = threadIdx.x, w = tid >> 6, lane = tid & 63, q = lane >> 4, r = lane & 15;
    int m0 = mb * 32;
    int grp = 16 + mb;
    int c0 = nb * 64;

    int c = c0 + w * 16 + r;
    int g = r & 3, d = c >> 2;
    size_t d_even = (size_t)(d & ~1);

    // stage weight slice into LDS (hi @0, lo @+65536), swizzled (r5-proven)
#pragma unroll
    for (int it = 0; it < 16; it++) {
        int m = it * 256 + tid;
        int row = m >> 6, ch = m & 63;
        int dst = row * 1024 + ((ch * 16) ^ ((row & 7) << 4));
        *(short8*)(wraw + dst) = *(const short8*)(a.whd_hi + (size_t)(c0 + row) * D + ch * 8);
        *(short8*)(wraw + 65536 + dst) = *(const short8*)(a.whd_lo + (size_t)(c0 + row) * D + ch * 8);
    }

    float wx0 = a.wxp_dec[0 * 2048 + c], wx1 = a.wxp_dec[1 * 2048 + c], wx2 = a.wxp_dec[2 * 2048 + c];
    float wx3 = a.wxp_dec[3 * 2048 + c], wx4 = a.wxp_dec[4 * 2048 + c];
    float zgc[2][4], creg[2][4];
#pragma unroll
    for (int mi = 0; mi < 2; mi++)
#pragma unroll
        for (int rr = 0; rr < 4; rr++) {
            int b = m0 + mi * 16 + q * 4 + rr;
            zgc[mi][rr] = a.zg[(size_t)b * 2048 + c];
            creg[mi][rr] = a.c32_d[(size_t)b * D + d];
        }

    if (tid < 32) {
        const float* p = a.data + (size_t)(m0 + tid) * (5 * (T + 1));
#pragma unroll
        for (int j = 0; j < 5; j++) smx[0][tid * 5 + j] = p[j];
    }
    __syncthreads();

    int crow = w * 16 + r;
    const char* pH = wraw + crow * 1024;
    const char* pL = wraw + 65536 + crow * 1024;
    int sw = (crow & 7) << 4;
    int q16 = q * 16;

    for (int t = 0; t < T; t++) {
        int pi = t & 1;
        const unsigned short* __restrict__ hph = a.hs_hi + (size_t)t * B * D;
        const unsigned short* __restrict__ hpl = a.hlo_pp + (size_t)pi * B * D;
        f32x4 acc0 = {0.f, 0.f, 0.f, 0.f}, acc1 = {0.f, 0.f, 0.f, 0.f};
#pragma unroll
        for (int ki = 0; ki < 16; ki++) {
            int kb = ki * 32 + q * 8;
            short8 bh = *(const short8*)(pH + ((ki * 64 + q16) ^ sw));
            short8 bl = *(const short8*)(pL + ((ki * 64 + q16) ^ sw));
            short8 a0h = *(const short8*)(hph + (size_t)(m0 + r) * D + kb);
            short8 a1h = *(const short8*)(hph + (size_t)(m0 + 16 + r) * D + kb);
            short8 a0l = *(const short8*)(hpl + (size_t)(m0 + r) * D + kb);
            short8 a1l = *(const short8*)(hpl + (size_t)(m0 + 16 + r) * D + kb);
            acc0 = __builtin_amdgcn_mfma_f32_16x16x32_bf16(a0h, bh, acc0, 0, 0, 0);
            acc1 = __builtin_amdgcn_mfma_f32_16x16x32_bf16(a1h, bh, acc1, 0, 0, 0);
            acc0 = __builtin_amdgcn_mfma_f32_16x16x32_bf16(a0l, bh, acc0, 0, 0, 0);
            acc1 = __builtin_amdgcn_mfma_f32_16x16x32_bf16(a1l, bh, acc1, 0, 0, 0);
            acc0 = __builtin_amdgcn_mfma_f32_16x16x32_bf16(a0h, bl, acc0, 0, 0, 0);
            acc1 = __builtin_amdgcn_mfma_f32_16x16x32_bf16(a1h, bl, acc1, 0, 0, 0);
        }
        if (t + 1 < T && tid < 32) {
            const float* p = a.data + (size_t)(m0 + tid) * (5 * (T + 1)) + (size_t)(t + 1) * 5;
#pragma unroll
            for (int j = 0; j < 5; j++) smx[(t + 1) & 1][tid * 5 + j] = p[j];
        }
        unsigned short* __restrict__ hnh = a.hs_hi + (size_t)(t + 1) * B * D;
        unsigned short* __restrict__ hnl = a.hlo_pp + (size_t)(1 - pi) * B * D;
        const float* xb = smx[t & 1];
#pragma unroll
        for (int mi = 0; mi < 2; mi++) {
            f32x4 acc = mi ? acc1 : acc0;
#pragma unroll
            for (int rr = 0; rr < 4; rr++) {
                int brow = mi * 16 + q * 4 + rr;
                float v = acc[rr] + zgc[mi][rr] + xb[brow * 5 + 0] * wx0 + xb[brow * 5 + 1] * wx1 +
                          xb[brow * 5 + 2] * wx2 + xb[brow * 5 + 3] * wx3 + xb[brow * 5 + 4] * wx4;
                float hnew = lstm_quad(v, g, creg[mi][rr]);
                store_h_pair<LOCAL>(hnew, r, hnh, hnl, (size_t)(m0 + brow) * D + d_even);
            }
        }
        group_barrier<LOCAL>(a.flags, a.go, a.ctrs, grp, nb, 32, (unsigned)(t + 1));
    }
}

DEVI void run_encout(const CoopArgs& a, float* smem) {
    int b = blockIdx.x, tid = threadIdx.x;
    // final encoder h is in ping-pong slot 0 (T=250 even)
    if (tid < 128) {
        smem[tid]       = bf2f(a.hf_hi[(size_t)b * H + tid])       + bf2f(a.hf_lo[(size_t)b * H + tid]);
        smem[tid + 128] = bf2f(a.hf_hi[(size_t)b * H + tid + 128]) + bf2f(a.hf_lo[(size_t)b * H + tid + 128]);
        smem[tid + 256] = bf2f(a.hb_hi[(size_t)b * H + tid])       + bf2f(a.hb_lo[(size_t)b * H + tid]);
        smem[tid + 384] = bf2f(a.hb_hi[(size_t)b * H + tid + 128]) + bf2f(a.hb_lo[(size_t)b * H + tid + 128]);
    }
    __syncthreads();
    if (tid < 128) {
        float mean = a.eob[tid], lv = a.eob[Z + tid];
        for (int k = 0; k < 2 * H; k++) {
            float h = smem[k];
            mean += h * a.eoW[(size_t)k * 2 * Z + tid];
            lv += h * a.eoW[(size_t)k * 2 * Z + Z + tid];
        }
        float z = mean + __expf(0.5f * lv) * a.eps[(size_t)b * Z + tid];
        a.out[OUT_ZM + (size_t)b * Z + tid] = mean;
        a.out[OUT_ZL + (size_t)b * Z + tid] = lv;
        a.zbuf[(size_t)b * Z + tid] = z;
    }
    __syncthreads();
}

DEVI void run_init_zg(const CoopArgs& a, float* smem) {
    int bid = blockIdx.x, tid = threadIdx.x;
    if (bid < 64) {
        int cc = (bid & 3) * 256 + tid;
        int b0 = (bid >> 2) * 16;
        for (int i = tid; i < 16 * Z; i += 256)
            smem[i] = a.zbuf[(size_t)(b0 + (i >> 7)) * Z + (i & 127)];
        __syncthreads();
        float acc[16];
        float bias = a.ib[cc];
#pragma unroll
        for (int bb = 0; bb < 16; bb++) acc[bb] = bias;
        for (int k = 0; k < Z; k++) {
            float wv = a.iW[(size_t)k * 1024 + cc];
#pragma unroll
            for (int bb = 0; bb < 16; bb++) acc[bb] += smem[bb * 128 + k] * wv;
        }
        for (int bb = 0; bb < 16; bb++) {
            float v = tanh_(acc[bb]);
            int b = b0 + bb;
            if (cc < D) {
                unsigned short hi = f2bf(v);
                a.hs_hi[(size_t)b * D + cc] = hi;
                a.hlo_pp[(size_t)b * D + cc] = f2bf(v - bf2f(hi));
            } else {
                a.c32_d[(size_t)b * D + (cc - D)] = v;
            }
        }
    } else if (bid < 192) {
        int bid2 = bid - 64;
        int cc = (bid2 & 7) * 256 + tid;
        int b0 = (bid2 >> 3) * 16;
        for (int i = tid; i < 16 * Z; i += 256)
            smem[i] = a.zbuf[(size_t)(b0 + (i >> 7)) * Z + (i & 127)];
        __syncthreads();
        float acc[16];
        float db_c = a.db[cc];
#pragma unroll
        for (int bb = 0; bb < 16; bb++) acc[bb] = db_c;
        for (int k = 0; k < Z; k++) {
            float wv = a.dWx[(size_t)(5 + k) * 2048 + cc];
#pragma unroll
            for (int bb = 0; bb < 16; bb++) acc[bb] += smem[bb * 128 + k] * wv;
        }
        int n = 4 * (cc & 511) + (cc >> 9);
#pragma unroll
        for (int bb = 0; bb < 16; bb++) a.zg[(size_t)(b0 + bb) * 2048 + n] = acc[bb];
    }
    __syncthreads();
}

__global__ __launch_bounds__(256, 1) void k_coop(CoopArgs a) {
    __shared__ float smem[2048];
    __shared__ float smx[2][160];
    __shared__ int s_info[2];
    __shared__ __align__(16) char wraw[131072];  // weight slice: hi @0, lo @65536

    // --- dynamic XCD registration: groups become XCD-local BY CONSTRUCTION ---
    if (threadIdx.x == 0) {
        unsigned x;
        asm volatile("s_getreg_b32 %0, hwreg(HW_REG_XCC_ID)" : "=s"(x));
        x &= 7;
        s_info[0] = (int)x;
        s_info[1] = (int)atomicAdd(a.reg_cnt + x * 32, 1u);  // device-scope
    }
    __syncthreads();
    int xcd = s_info[0], slot = s_info[1];
    cg::this_grid().sync();
    // grid-uniform verdict: every XCD must host exactly 32 of the 256 blocks
    bool local = (slot < 32);
#pragma unroll
    for (int i = 0; i < 8; i++) local = local && (a.reg_cnt[i * 32] == 32u);

    if (local) {
        // encoder: 2 groups per XCD (16 blocks each): dir = upper/lower slot half
        run_encoder<true>(a, smx, wraw, slot >> 4, xcd, slot & 15);
    } else {
        int bid = blockIdx.x;
        run_encoder<false>(a, smx, wraw, bid >> 7, (bid >> 4) & 7, bid & 15);
    }
    cg::this_grid().sync();
    run_encout(a, smem);
    cg::this_grid().sync();
    run_init_zg(a, smem);
    cg::this_grid().sync();
    if (local) {
        // decoder: 1 group per XCD (all 32 blocks)
        run_decoder<true>(a, smx, wraw, xcd, slot);
    } else {
        run_decoder<false>(a, smx, wraw, blockIdx.x >> 5, blockIdx.x & 31);
    }
}

// ---------------- mix GEMM ----------------
__global__ __launch_bounds__(256) void k_mix(const unsigned short* __restrict__ hs,
                                             const unsigned short* __restrict__ mixwt,
                                             const float* __restrict__ mb, float* __restrict__ dout) {
    int tid = threadIdx.x, wave = tid >> 6, lane = tid & 63, q = lane >> 4, r = lane & 15;
    int m0 = blockIdx.y * 64 + (wave >> 1) * 32;
    int n0 = blockIdx.x * 64 + (wave & 1) * 32;
    const unsigned short* A = hs + (size_t)B * D;  // ring slots 1..T
    f32x4 acc[2][2];
#pragma unroll
    for (int mi = 0; mi < 2; mi++)
#pragma unroll
        for (int ni = 0; ni < 2; ni++) acc[mi][ni] = {0.f, 0.f, 0.f, 0.f};
#pragma unroll 4
    for (int kk = 0; kk < D; kk += 32) {
        int kb = kk + q * 8;
        short8 a0 = *(const short8*)(A + (size_t)(m0 + r) * D + kb);
        short8 a1 = *(const short8*)(A + (size_t)(m0 + 16 + r) * D + kb);
        short8 b0 = *(const short8*)(mixwt + (size_t)(n0 + r) * D + kb);
        short8 b1 = *(const short8*)(mixwt + (size_t)(n0 + 16 + r) * D + kb);
        acc[0][0] = __builtin_amdgcn_mfma_f32_16x16x32_bf16(a0, b0, acc[0][0], 0, 0, 0);
        acc[0][1] = __builtin_amdgcn_mfma_f32_16x16x32_bf16(a0, b1, acc[0][1], 0, 0, 0);
        acc[1][0] = __builtin_amdgcn_mfma_f32_16x16x32_bf16(a1, b0, acc[1][0], 0, 0, 0);
        acc[1][1] = __builtin_amdgcn_mfma_f32_16x16x32_bf16(a1, b1, acc[1][1], 0, 0, 0);
    }
#pragma unroll
    for (int ni = 0; ni < 2; ni++) {
        int ncol = n0 + ni * 16 + r;
        if (ncol < P) {
            float bias = mb[ncol];
#pragma unroll
            for (int mi = 0; mi < 2; mi++) {
#pragma unroll
                for (int rr = 0; rr < 4; rr++) {
                    int m = m0 + mi * 16 + q * 4 + rr;
                    int b = m & 255, t = m >> 8;
                    dout[((size_t)b * T + t) * P + ncol] = acc[mi][ni][rr] + bias;
                }
            }
        }
    }
}

// ---------------- per-row epilogue ----------------
__global__ void k_post(float* __restrict__ dout) {
    __shared__ float row[P];
    int rid = blockIdx.x;
    int tid = threadIdx.x;
    float* base = dout + (size_t)rid * P;
    float v = 0.f;
    if (tid < P) { v = base[tid]; row[tid] = v; }
    __syncthreads();
    if (tid < P) {
        float o;
        if (tid < KMIX) {
            float mx = row[0];
            for (int i = 1; i < KMIX; i++) mx = fmaxf(mx, row[i]);
            float sm = 0.f;
            for (int i = 0; i < KMIX; i++) sm += __expf(row[i] - mx);
            o = __expf(v - mx) / sm;
        } else if (tid < 3 * KMIX) o = v;
        else if (tid < 5 * KMIX) o = __expf(v);
        else if (tid < 6 * KMIX) o = tanh_(v);
        else o = v;
        base[tid] = o;
    }
}

extern "C" void kernel_launch(void* const* d_in, const int* in_sizes, int n_in,
                              void* d_out, int out_size, void* d_ws, size_t ws_size,
                              hipStream_t stream) {
    const float* data = (const float*)d_in[0];
    const float* eps  = (const float*)d_in[1];
    const float* eWxf = (const float*)d_in[2];
    const float* eWhf = (const float*)d_in[3];
    const float* ebf  = (const float*)d_in[4];
    const float* eWxb = (const float*)d_in[5];
    const float* eWhb = (const float*)d_in[6];
    const float* ebb  = (const float*)d_in[7];
    const float* eoW  = (const float*)d_in[8];
    const float* eob  = (const float*)d_in[9];
    const float* iW   = (const float*)d_in[10];
    const float* ib   = (const float*)d_in[11];
    const float* dWx  = (const float*)d_in[12];
    const float* dWh  = (const float*)d_in[13];
    const float* db   = (const float*)d_in[14];
    const float* mW   = (const float*)d_in[15];
    const float* mb   = (const float*)d_in[16];
    float* out = (float*)d_out;

    char* base = (char*)d_ws;
    size_t off = 0;
    auto alloc = [&](size_t bytes) -> char* {
        off = (off + 255) & ~(size_t)255;
        char* p = base + off;
        off += bytes;
        return p;
    };
    unsigned short* whd_hi = (unsigned short*)alloc((size_t)2048 * 512 * 2);
    unsigned short* whd_lo = (unsigned short*)alloc((size_t)2048 * 512 * 2);
    unsigned short* whf_hi = (unsigned short*)alloc((size_t)1024 * 256 * 2);
    unsigned short* whf_lo = (unsigned short*)alloc((size_t)1024 * 256 * 2);
    unsigned short* whb_hi = (unsigned short*)alloc((size_t)1024 * 256 * 2);
    unsigned short* whb_lo = (unsigned short*)alloc((size_t)1024 * 256 * 2);
    unsigned short* mixwt  = (unsigned short*)alloc((size_t)128 * 512 * 2);
    float* wxp_dec = (float*)alloc((size_t)5 * 2048 * 4);
    float* wxp_ef  = (float*)alloc((size_t)5 * 1024 * 4);
    float* wxp_eb  = (float*)alloc((size_t)5 * 1024 * 4);
    float* bp_ef   = (float*)alloc((size_t)1024 * 4);
    float* bp_eb   = (float*)alloc((size_t)1024 * 4);
    unsigned short* hf_hi = (unsigned short*)alloc((size_t)2 * B * H * 2);
    unsigned short* hf_lo = (unsigned short*)alloc((size_t)2 * B * H * 2);
    unsigned short* hb_hi = (unsigned short*)alloc((size_t)2 * B * H * 2);
    unsigned short* hb_lo = (unsigned short*)alloc((size_t)2 * B * H * 2);
    float* c32_d  = (float*)alloc((size_t)B * D * 4);
    unsigned short* hs_hi = (unsigned short*)alloc((size_t)(T + 1) * B * D * 2);
    unsigned short* hlo_pp = (unsigned short*)alloc((size_t)2 * B * D * 2);
    float* zbuf = (float*)alloc((size_t)B * Z * 4);
    float* zg   = (float*)alloc((size_t)B * 2048 * 4);
    unsigned* flags = (unsigned*)alloc((size_t)24 * 1024 * 4);
    unsigned* go    = (unsigned*)alloc((size_t)24 * 32 * 4);
    unsigned* ctrs  = (unsigned*)alloc((size_t)24 * 32 * 4);
    unsigned* reg_cnt = (unsigned*)alloc((size_t)256 * 4);
    (void)ws_size; (void)in_sizes; (void)n_in; (void)out_size;

    k_zero<<<256, 256, 0, stream>>>(hf_hi, hb_hi, hf_lo, hb_lo, flags, go, ctrs, reg_cnt);
    k_pack_whT<512><<<dim3(64, 16), dim3(32, 8), 0, stream>>>(dWh, whd_hi, whd_lo);
    k_pack_whT<256><<<dim3(32, 8), dim3(32, 8), 0, stream>>>(eWhf, whf_hi, whf_lo);
    k_pack_whT<256><<<dim3(32, 8), dim3(32, 8), 0, stream>>>(eWhb, whb_hi, whb_lo);
    k_pack_mix<<<256, 256, 0, stream>>>(mW, mixwt);
    k_pack_cols<<<40, 256, 0, stream>>>(dWx, wxp_dec, 512, 2048);
    k_pack_cols<<<20, 256, 0, stream>>>(eWxf, wxp_ef, 256, 1024);
    k_pack_cols<<<20, 256, 0, stream>>>(eWxb, wxp_eb, 256, 1024);
    k_pack_cols<<<4, 256, 0, stream>>>(ebf, bp_ef, 256, 1024);
    k_pack_cols<<<4, 256, 0, stream>>>(ebb, bp_eb, 256, 1024);

    CoopArgs ca;
    ca.data = data; ca.eps = eps;
    ca.whf_hi = whf_hi; ca.whf_lo = whf_lo; ca.whb_hi = whb_hi; ca.whb_lo = whb_lo;
    ca.whd_hi = whd_hi; ca.whd_lo = whd_lo;
    ca.wxp_ef = wxp_ef; ca.wxp_eb = wxp_eb; ca.wxp_dec = wxp_dec;
    ca.bp_ef = bp_ef; ca.bp_eb = bp_eb;
    ca.eoW = eoW; ca.eob = eob; ca.iW = iW; ca.ib = ib; ca.dWx = dWx; ca.db = db;
    ca.hf_hi = hf_hi; ca.hf_lo = hf_lo; ca.hb_hi = hb_hi; ca.hb_lo = hb_lo;
    ca.c32_d = c32_d;
    ca.hs_hi = hs_hi; ca.hlo_pp = hlo_pp;
    ca.zbuf = zbuf; ca.zg = zg; ca.out = out;
    ca.flags = flags; ca.go = go; ca.ctrs = ctrs; ca.reg_cnt = reg_cnt;

    void* kp[] = { &ca };
    hipLaunchCooperativeKernel((void*)k_coop, dim3(256), dim3(256), kp, 0, stream);

    k_mix<<<dim3(2, 1000), 256, 0, stream>>>(hs_hi, mixwt, mb, out);
    k_post<<<64000, 128, 0, stream>>>(out);
}

// Round 8
// 5241.235 us; speedup vs baseline: 1.1066x; 1.0096x over previous
//
#include <hip/hip_runtime.h>
#include <hip/hip_cooperative_groups.h>

namespace cg = cooperative_groups;

typedef __attribute__((ext_vector_type(8))) short short8;
typedef __attribute__((ext_vector_type(4))) float f32x4;

static constexpr int B = 256, T = 250, Z = 128, H = 256, D = 512, KMIX = 20, P = 123;
static constexpr int PARAMS_N = B * T * P;
static constexpr int OUT_ZM = PARAMS_N;
static constexpr int OUT_ZL = PARAMS_N + B * Z;

#define DEVI static __device__ __forceinline__

DEVI unsigned short f2bf(float f) {
    unsigned int u = __float_as_uint(f);
    u += 0x7fffu + ((u >> 16) & 1u);
    return (unsigned short)(u >> 16);
}
DEVI float bf2f(unsigned short s) { return __uint_as_float(((unsigned int)s) << 16); }
DEVI float sigm(float x) { return 1.0f / (1.0f + __expf(-x)); }
DEVI float tanh_(float x) {
    x = fminf(fmaxf(x, -15.0f), 15.0f);
    float e = __expf(2.0f * x);
    return (e - 1.0f) / (e + 1.0f);
}

// L2-executed atomic fetch_add (r7-proven correct). sc0 = return old value.
DEVI unsigned l2_fetch_add(unsigned* p, unsigned val) {
    unsigned old;
    asm volatile("global_atomic_add %0, %1, %2, off sc0\n\ts_waitcnt vmcnt(0)"
                 : "=v"(old)
                 : "v"(p), "v"(val)
                 : "memory");
    return old;
}

// ---------------- zero-init (ws is poisoned 0xAA every replay) ----------------
__global__ void k_zero(unsigned short* h1, unsigned short* h2,
                       unsigned short* h1l, unsigned short* h2l,
                       unsigned* flags, unsigned* go, unsigned* ctrs, unsigned* reg_cnt) {
    int i = blockIdx.x * 256 + threadIdx.x;  // 65536 = B*H
    h1[i] = 0; h2[i] = 0; h1l[i] = 0; h2l[i] = 0;
    if (i < 24 * 1024) flags[i] = 0;  // 24 groups x 32 blocks x 32 uints (fallback)
    if (i < 24 * 32) go[i] = 0;       // 24 groups x 1 line (fallback)
    if (i < 24 * 32) ctrs[i] = 0;     // 24 groups x 1 line (LOCAL L2 counters)
    if (i < 256) reg_cnt[i] = 0;      // 8 XCDs x 32 uints
}

// ---------------- weight packing ----------------
// Wh [K=HID][4*HID] fp32 -> hi/lo [4*HID][HID] bf16, rows packed n = 4*d + g
template <int HID>
__global__ void k_pack_whT(const float* __restrict__ Wh, unsigned short* __restrict__ ohi,
                           unsigned short* __restrict__ olo) {
    constexpr int N4 = 4 * HID;
    __shared__ float tile[32][33];
    int c0 = blockIdx.x * 32, k0 = blockIdx.y * 32;
    int tx = threadIdx.x, ty = threadIdx.y;
#pragma unroll
    for (int ii = 0; ii < 4; ii++)
        tile[ty + 8 * ii][tx] = Wh[(size_t)(k0 + ty + 8 * ii) * N4 + c0 + tx];
    __syncthreads();
#pragma unroll
    for (int ii = 0; ii < 4; ii++) {
        int j = ty + 8 * ii;
        int c = c0 + j;
        int g = c / HID, d = c % HID;
        float w = tile[tx][j];
        unsigned short hi = f2bf(w);
        unsigned short lo = f2bf(w - bf2f(hi));
        size_t o = (size_t)(4 * d + g) * HID + k0 + tx;
        ohi[o] = hi;
        olo[o] = lo;
    }
}

// mix_W [512][123] fp32 -> [128][512] bf16 (zero padded cols >=123)
__global__ void k_pack_mix(const float* __restrict__ W, unsigned short* __restrict__ out) {
    int idx = blockIdx.x * 256 + threadIdx.x;  // 128*512
    int n = idx >> 9, k = idx & 511;
    out[idx] = (n < P) ? f2bf(W[(size_t)k * P + n]) : (unsigned short)0;
}

// fp32 column permutation into packed gate order
__global__ void k_pack_cols(const float* __restrict__ in, float* __restrict__ out, int HID, int N4) {
    int idx = blockIdx.x * 256 + threadIdx.x;
    int row = idx / N4, n = idx % N4;
    out[idx] = in[(size_t)row * N4 + (n & 3) * HID + (n >> 2)];
}

// ---------------- cooperative persistent kernel ----------------
struct CoopArgs {
    const float* data;
    const float* eps;
    const unsigned short *whf_hi, *whf_lo, *whb_hi, *whb_lo, *whd_hi, *whd_lo;
    const float *wxp_ef, *wxp_eb, *wxp_dec, *bp_ef, *bp_eb;
    const float *eoW, *eob, *iW, *ib, *dWx, *db;
    unsigned short *hf_hi, *hf_lo, *hb_hi, *hb_lo;  // [2][B][H] ping-pong
    float* c32_d;
    unsigned short* hs_hi;   // [T+1][B][D] ring (k_mix input; LOCAL: written OFF the critical path)
    unsigned short* hhi_pp;  // [2][B][D] hi ping-pong (LOCAL decoder recurrence reads this, L2-hot)
    unsigned short* hlo_pp;  // [2][B][D] lo ping-pong
    float *zbuf, *zg;
    float* out;
    unsigned* flags;    // [24 groups][32 blocks][32 uints] (fallback arrivals)
    unsigned* go;       // [24 groups][32 uints] (fallback broadcast)
    unsigned* ctrs;     // [24 groups][32 uints] cumulative L2 arrival counters (LOCAL)
    unsigned* reg_cnt;  // [8 XCDs][32 uints] dynamic placement registration
};

// Group barrier (encoder LOCAL + all fallback). r7-proven.
// LOCAL: cumulative L2 counter; arrive = L2 atomic +1 after entry sync drained
// stores into the same L2; wait = poll L2 atomic +0; acquire = buffer_inv sc0.
// Fallback: agent-scope leader/go barrier (baseline-proven).
template <bool LOCAL>
DEVI void group_barrier(unsigned* flags, unsigned* go, unsigned* ctrs, int grp, int myblk,
                        int nblk, unsigned stamp) {
    __syncthreads();
    int tid = threadIdx.x;
    if constexpr (LOCAL) {
        if (tid == 0) {
            unsigned* cp = ctrs + (size_t)grp * 32;
            unsigned target = (unsigned)nblk * stamp;
            unsigned v = l2_fetch_add(cp, 1u) + 1u;
            while (v < target) {
                __builtin_amdgcn_s_sleep(1);
                v = l2_fetch_add(cp, 0u);
            }
        }
        __syncthreads();
        asm volatile("buffer_inv sc0" ::: "memory");  // acquire: L1 inv; L2 holds fresh h
    } else {
        unsigned* gf = flags + (size_t)grp * 1024;
        if (tid == 0)
            __hip_atomic_store(gf + myblk * 32, stamp, __ATOMIC_RELAXED, __HIP_MEMORY_SCOPE_AGENT);
        if (myblk == 0 && tid < 64) {
            for (;;) {
                unsigned v = (tid < nblk)
                    ? __hip_atomic_load(gf + tid * 32, __ATOMIC_RELAXED, __HIP_MEMORY_SCOPE_AGENT)
                    : stamp;
                if (__all(v >= stamp)) break;
                __builtin_amdgcn_s_sleep(1);
            }
            if (tid == 0)
                __hip_atomic_store(go + grp * 32, stamp, __ATOMIC_RELAXED, __HIP_MEMORY_SCOPE_AGENT);
        }
        if (tid == 0) {
            while (__hip_atomic_load(go + grp * 32, __ATOMIC_RELAXED, __HIP_MEMORY_SCOPE_AGENT) < stamp)
                __builtin_amdgcn_s_sleep(1);
            __builtin_amdgcn_fence(__ATOMIC_ACQUIRE, "agent");
        }
        __syncthreads();
    }
}

// quad-shuffle gate gather + pointwise update; c lives in a register (quad-redundant)
DEVI float lstm_quad(float v, int g, float& c) {
    float s1 = __shfl_xor(v, 1, 64);
    float s2 = __shfl_xor(v, 2, 64);
    float s3 = __shfl_xor(v, 3, 64);
    float gi, gf, gg, go;
    if (g == 0)      { gi = v;  gf = s1; gg = s2; go = s3; }
    else if (g == 1) { gi = s1; gf = v;  gg = s3; go = s2; }
    else if (g == 2) { gi = s2; gf = s3; gg = v;  go = s1; }
    else             { gi = s3; gf = s2; gg = s1; go = v;  }
    float cnew = sigm(gf) * c + sigm(gi) * tanh_(gg);
    c = cnew;
    return sigm(go) * tanh_(cnew);
}

// packed 4B stores of (hi_d, hi_{d+1}) and (lo_d, lo_{d+1}).
// LOCAL: plain stores -> shared XCD L2 (r1/r2-proven). Fallback: agent-scope.
template <bool LOCAL>
DEVI void store_h_pair(float hnew, int r, unsigned short* __restrict__ hnh,
                       unsigned short* __restrict__ hnl, size_t o_even) {
    unsigned short hi = f2bf(hnew);
    float lo = hnew - bf2f(hi);
    float hp = __shfl_xor(hnew, 4, 64);   // partner lane: d ^ 1, same gate
    unsigned short hip = f2bf(hp);
    float lop = hp - bf2f(hip);
    if ((r & 7) == 0) {
        unsigned pk = (unsigned)hi | ((unsigned)hip << 16);
        if constexpr (LOCAL)
            *(unsigned*)(hnh + o_even) = pk;
        else
            __hip_atomic_store((unsigned*)(hnh + o_even), pk, __ATOMIC_RELAXED, __HIP_MEMORY_SCOPE_AGENT);
    } else if ((r & 7) == 1) {
        unsigned pk = (unsigned)f2bf(lo) | ((unsigned)f2bf(lop) << 16);
        if constexpr (LOCAL)
            *(unsigned*)(hnl + o_even) = pk;
        else
            __hip_atomic_store((unsigned*)(hnl + o_even), pk, __ATOMIC_RELAXED, __HIP_MEMORY_SCOPE_AGENT);
    }
}

template <bool LOCAL>
DEVI void run_encoder(const CoopArgs& a, float (*smx)[160], char* wraw, int dir, int mb, int nb) {
    int tid = threadIdx.x, w = tid >> 6, lane = tid & 63, q = lane >> 4, r = lane & 15;
    int m0 = mb * 32;
    const unsigned short* __restrict__ whi = dir ? a.whb_hi : a.whf_hi;
    const unsigned short* __restrict__ wlo = dir ? a.whb_lo : a.whf_lo;
    const float* __restrict__ wxp = dir ? a.wxp_eb : a.wxp_ef;
    const float* __restrict__ bp = dir ? a.bp_eb : a.bp_ef;
    unsigned short* __restrict__ hhi = dir ? a.hb_hi : a.hf_hi;
    unsigned short* __restrict__ hlo = dir ? a.hb_lo : a.hf_lo;
    int grp = dir * 8 + mb;
    int c0 = nb * 64;

    int c = c0 + w * 16 + r;
    int g = r & 3, d = c >> 2;
    size_t d_even = (size_t)(d & ~1);

    // stage weight slice into LDS (hi @0, lo @+65536), swizzled (r5-proven)
#pragma unroll
    for (int it = 0; it < 8; it++) {
        int m = it * 256 + tid;
        int row = m >> 5, ch = m & 31;
        int dst = row * 512 + ((ch * 16) ^ ((row & 7) << 4));
        *(short8*)(wraw + dst) = *(const short8*)(whi + (size_t)(c0 + row) * H + ch * 8);
        *(short8*)(wraw + 65536 + dst) = *(const short8*)(wlo + (size_t)(c0 + row) * H + ch * 8);
    }

    float wx0 = wxp[0 * 1024 + c], wx1 = wxp[1 * 1024 + c], wx2 = wxp[2 * 1024 + c];
    float wx3 = wxp[3 * 1024 + c], wx4 = wxp[4 * 1024 + c];
    float bias = bp[c];
    float creg[2][4];
#pragma unroll
    for (int mi = 0; mi < 2; mi++)
#pragma unroll
        for (int rr = 0; rr < 4; rr++) creg[mi][rr] = 0.f;

    // stage x(t=0) into LDS buf 0
    {
        int tt0 = dir ? 250 : 1;
        if (tid < 32) {
            const float* p = a.data + (size_t)(m0 + tid) * (5 * (T + 1)) + (size_t)tt0 * 5;
#pragma unroll
            for (int j = 0; j < 5; j++) smx[0][tid * 5 + j] = p[j];
        }
    }
    __syncthreads();

    int crow = w * 16 + r;
    const char* pH = wraw + crow * 512;
    const char* pL = wraw + 65536 + crow * 512;
    int sw = (crow & 7) << 4;
    int q16 = q * 16;

    for (int t = 0; t < T; t++) {
        int pi = t & 1;
        const unsigned short* __restrict__ hph = hhi + (size_t)pi * B * H;
        const unsigned short* __restrict__ hpl = hlo + (size_t)pi * B * H;
        f32x4 acc0 = {0.f, 0.f, 0.f, 0.f}, acc1 = {0.f, 0.f, 0.f, 0.f};
#pragma unroll
        for (int ki = 0; ki < 8; ki++) {
            int kb = ki * 32 + q * 8;
            short8 bh = *(const short8*)(pH + ((ki * 64 + q16) ^ sw));
            short8 bl = *(const short8*)(pL + ((ki * 64 + q16) ^ sw));
            short8 a0h = *(const short8*)(hph + (size_t)(m0 + r) * H + kb);
            short8 a1h = *(const short8*)(hph + (size_t)(m0 + 16 + r) * H + kb);
            short8 a0l = *(const short8*)(hpl + (size_t)(m0 + r) * H + kb);
            short8 a1l = *(const short8*)(hpl + (size_t)(m0 + 16 + r) * H + kb);
            acc0 = __builtin_amdgcn_mfma_f32_16x16x32_bf16(a0h, bh, acc0, 0, 0, 0);
            acc1 = __builtin_amdgcn_mfma_f32_16x16x32_bf16(a1h, bh, acc1, 0, 0, 0);
            acc0 = __builtin_amdgcn_mfma_f32_16x16x32_bf16(a0l, bh, acc0, 0, 0, 0);
            acc1 = __builtin_amdgcn_mfma_f32_16x16x32_bf16(a1l, bh, acc1, 0, 0, 0);
            acc0 = __builtin_amdgcn_mfma_f32_16x16x32_bf16(a0h, bl, acc0, 0, 0, 0);
            acc1 = __builtin_amdgcn_mfma_f32_16x16x32_bf16(a1h, bl, acc1, 0, 0, 0);
        }
        // prefetch x(t+1) into the other LDS buffer (overlaps epilogue)
        if (t + 1 < T && tid < 32) {
            int ttn = dir ? (249 - t) : (2 + t);
            const float* p = a.data + (size_t)(m0 + tid) * (5 * (T + 1)) + (size_t)ttn * 5;
#pragma unroll
            for (int j = 0; j < 5; j++) smx[(t + 1) & 1][tid * 5 + j] = p[j];
        }
        unsigned short* __restrict__ hnh = hhi + (size_t)(1 - pi) * B * H;
        unsigned short* __restrict__ hnl = hlo + (size_t)(1 - pi) * B * H;
        const float* xb = smx[t & 1];
#pragma unroll
        for (int mi = 0; mi < 2; mi++) {
            f32x4 acc = mi ? acc1 : acc0;
#pragma unroll
            for (int rr = 0; rr < 4; rr++) {
                int brow = mi * 16 + q * 4 + rr;
                float v = acc[rr] + bias + xb[brow * 5 + 0] * wx0 + xb[brow * 5 + 1] * wx1 +
                          xb[brow * 5 + 2] * wx2 + xb[brow * 5 + 3] * wx3 + xb[brow * 5 + 4] * wx4;
                float hnew = lstm_quad(v, g, creg[mi][rr]);
                store_h_pair<LOCAL>(hnew, r, hnh, hnl, (size_t)(m0 + brow) * H + d_even);
            }
        }
        group_barrier<LOCAL>(a.flags, a.go, a.ctrs, grp, nb, 16, (unsigned)(t + 1));
    }
}

template <bool LOCAL>
DEVI void run_decoder(const CoopArgs& a, float (*smx)[160], char* wraw, int mb, int nb) {
    int tid = threadIdx.x, w = tid >> 6, lane = tid & 63, q = lane >> 4, r = lane & 15;
    int m0 = mb * 32;
    int grp = 16 + mb;
    int c0 = nb * 64;

    int c = c0 + w * 16 + r;
    int g = r & 3, d = c >> 2;
    size_t d_even = (size_t)(d & ~1);

    // stage weight slice into LDS (hi @0, lo @+65536), swizzled (r5-proven)
#pragma unroll
    for (int it = 0; it < 16; it++) {
        int m = it * 256 + tid;
        int row = m >> 6, ch = m & 63;
        int dst = row * 1024 + ((ch * 16) ^ ((row & 7) << 4));
        *(short8*)(wraw + dst) = *(const short8*)(a.whd_hi + (size_t)(c0 + row) * D + ch * 8);
        *(short8*)(wraw + 65536 + dst) = *(const short8*)(a.whd_lo + (size_t)(c0 + row) * D + ch * 8);
    }

    float wx0 = a.wxp_dec[0 * 2048 + c], wx1 = a.wxp_dec[1 * 2048 + c], wx2 = a.wxp_dec[2 * 2048 + c];
    float wx3 = a.wxp_dec[3 * 2048 + c], wx4 = a.wxp_dec[4 * 2048 + c];
    float zgc[2][4], creg[2][4];
#pragma unroll
    for (int mi = 0; mi < 2; mi++)
#pragma unroll
        for (int rr = 0; rr < 4; rr++) {
            int b = m0 + mi * 16 + q * 4 + rr;
            zgc[mi][rr] = a.zg[(size_t)b * 2048 + c];
            creg[mi][rr] = a.c32_d[(size_t)b * D + d];
        }

    if (tid < 32) {
        const float* p = a.data + (size_t)(m0 + tid) * (5 * (T + 1));
#pragma unroll
        for (int j = 0; j < 5; j++) smx[0][tid * 5 + j] = p[j];
    }
    __syncthreads();

    int crow = w * 16 + r;
    const char* pH = wraw + crow * 1024;
    const char* pL = wraw + 65536 + crow * 1024;
    int sw = (crow & 7) << 4;
    int q16 = q * 16;

    for (int t = 0; t < T; t++) {
        int pi = t & 1;
        // RING-OFF-CRITICAL-PATH (r7 post-mortem): the t-loop's recurrence reads
        // the L2-HOT hi ping-pong (LOCAL) instead of the cold ring slot; ring
        // stores (cold HBM lines -> write-allocate round trips) are issued AFTER
        // arrive/poll, so their drain lands at the NEXT step's entry sync — a
        // full compute phase later — instead of serializing every barrier.
        const unsigned short* __restrict__ hph =
            LOCAL ? (a.hhi_pp + (size_t)pi * B * D) : (a.hs_hi + (size_t)t * B * D);
        const unsigned short* __restrict__ hpl = a.hlo_pp + (size_t)pi * B * D;
        f32x4 acc0 = {0.f, 0.f, 0.f, 0.f}, acc1 = {0.f, 0.f, 0.f, 0.f};
#pragma unroll
        for (int ki = 0; ki < 16; ki++) {
            int kb = ki * 32 + q * 8;
            short8 bh = *(const short8*)(pH + ((ki * 64 + q16) ^ sw));
            short8 bl = *(const short8*)(pL + ((ki * 64 + q16) ^ sw));
            short8 a0h = *(const short8*)(hph + (size_t)(m0 + r) * D + kb);
            short8 a1h = *(const short8*)(hph + (size_t)(m0 + 16 + r) * D + kb);
            short8 a0l = *(const short8*)(hpl + (size_t)(m0 + r) * D + kb);
            short8 a1l = *(const short8*)(hpl + (size_t)(m0 + 16 + r) * D + kb);
            acc0 = __builtin_amdgcn_mfma_f32_16x16x32_bf16(a0h, bh, acc0, 0, 0, 0);
            acc1 = __builtin_amdgcn_mfma_f32_16x16x32_bf16(a1h, bh, acc1, 0, 0, 0);
            acc0 = __builtin_amdgcn_mfma_f32_16x16x32_bf16(a0l, bh, acc0, 0, 0, 0);
            acc1 = __builtin_amdgcn_mfma_f32_16x16x32_bf16(a1l, bh, acc1, 0, 0, 0);
            acc0 = __builtin_amdgcn_mfma_f32_16x16x32_bf16(a0h, bl, acc0, 0, 0, 0);
            acc1 = __builtin_amdgcn_mfma_f32_16x16x32_bf16(a1h, bl, acc1, 0, 0, 0);
        }
        if (t + 1 < T && tid < 32) {
            const float* p = a.data + (size_t)(m0 + tid) * (5 * (T + 1)) + (size_t)(t + 1) * 5;
#pragma unroll
            for (int j = 0; j < 5; j++) smx[(t + 1) & 1][tid * 5 + j] = p[j];
        }
        const float* xb = smx[t & 1];
        unsigned ringw[8];  // packed hi words, valid on (r&7)==0 lanes
        if constexpr (LOCAL) {
            unsigned short* __restrict__ hnh = a.hhi_pp + (size_t)(1 - pi) * B * D;
            unsigned short* __restrict__ hnl = a.hlo_pp + (size_t)(1 - pi) * B * D;
#pragma unroll
            for (int mi = 0; mi < 2; mi++) {
                f32x4 acc = mi ? acc1 : acc0;
#pragma unroll
                for (int rr = 0; rr < 4; rr++) {
                    int brow = mi * 16 + q * 4 + rr;
                    float v = acc[rr] + zgc[mi][rr] + xb[brow * 5 + 0] * wx0 + xb[brow * 5 + 1] * wx1 +
                              xb[brow * 5 + 2] * wx2 + xb[brow * 5 + 3] * wx3 + xb[brow * 5 + 4] * wx4;
                    float hnew = lstm_quad(v, g, creg[mi][rr]);
                    unsigned short hi = f2bf(hnew);
                    float lo = hnew - bf2f(hi);
                    float hp = __shfl_xor(hnew, 4, 64);
                    unsigned short hip = f2bf(hp);
                    float lop = hp - bf2f(hip);
                    size_t o_even = (size_t)(m0 + brow) * D + d_even;
                    if ((r & 7) == 0) {
                        unsigned pk = (unsigned)hi | ((unsigned)hip << 16);
                        *(unsigned*)(hnh + o_even) = pk;  // L2-hot ping-pong (peers read this)
                        ringw[mi * 4 + rr] = pk;
                    } else if ((r & 7) == 1) {
                        unsigned pk = (unsigned)f2bf(lo) | ((unsigned)f2bf(lop) << 16);
                        *(unsigned*)(hnl + o_even) = pk;
                    }
                }
            }
            // barrier with ring stores off the critical path:
            __syncthreads();  // drains ONLY hot ping-pong stores (+ last step's ring, long done)
            if (tid == 0) {
                unsigned* cp = a.ctrs + (size_t)grp * 32;
                unsigned target = 32u * (unsigned)(t + 1);
                unsigned v = l2_fetch_add(cp, 1u) + 1u;  // arrive (clean vmcnt)
                while (v < target) {
                    __builtin_amdgcn_s_sleep(1);
                    v = l2_fetch_add(cp, 0u);
                }
            }
            // ring stores: fire-and-forget; non-tid0 waves issue during tid0's
            // poll; tid0 issues after its poll. Drained at NEXT entry sync.
            if ((r & 7) == 0) {
                unsigned short* __restrict__ ring = a.hs_hi + (size_t)(t + 1) * B * D;
#pragma unroll
                for (int mi = 0; mi < 2; mi++)
#pragma unroll
                    for (int rr = 0; rr < 4; rr++) {
                        int brow = mi * 16 + q * 4 + rr;
                        *(unsigned*)(ring + (size_t)(m0 + brow) * D + d_even) = ringw[mi * 4 + rr];
                    }
            }
            __builtin_amdgcn_s_barrier();  // raw: no vmcnt drain here
            asm volatile("buffer_inv sc0" ::: "memory");  // acquire: L1 inv; L2 holds fresh h
        } else {
            unsigned short* __restrict__ hnh = a.hs_hi + (size_t)(t + 1) * B * D;
            unsigned short* __restrict__ hnl = a.hlo_pp + (size_t)(1 - pi) * B * D;
#pragma unroll
            for (int mi = 0; mi < 2; mi++) {
                f32x4 acc = mi ? acc1 : acc0;
#pragma unroll
                for (int rr = 0; rr < 4; rr++) {
                    int brow = mi * 16 + q * 4 + rr;
                    float v = acc[rr] + zgc[mi][rr] + xb[brow * 5 + 0] * wx0 + xb[brow * 5 + 1] * wx1 +
                              xb[brow * 5 + 2] * wx2 + xb[brow * 5 + 3] * wx3 + xb[brow * 5 + 4] * wx4;
                    float hnew = lstm_quad(v, g, creg[mi][rr]);
                    store_h_pair<false>(hnew, r, hnh, hnl, (size_t)(m0 + brow) * D + d_even);
                }
            }
            group_barrier<false>(a.flags, a.go, a.ctrs, grp, nb, 32, (unsigned)(t + 1));
        }
    }
}

DEVI void run_encout(const CoopArgs& a, float* smem) {
    int b = blockIdx.x, tid = threadIdx.x;
    // final encoder h is in ping-pong slot 0 (T=250 even)
    if (tid < 128) {
        smem[tid]       = bf2f(a.hf_hi[(size_t)b * H + tid])       + bf2f(a.hf_lo[(size_t)b * H + tid]);
        smem[tid + 128] = bf2f(a.hf_hi[(size_t)b * H + tid + 128]) + bf2f(a.hf_lo[(size_t)b * H + tid + 128]);
        smem[tid + 256] = bf2f(a.hb_hi[(size_t)b * H + tid])       + bf2f(a.hb_lo[(size_t)b * H + tid]);
        smem[tid + 384] = bf2f(a.hb_hi[(size_t)b * H + tid + 128]) + bf2f(a.hb_lo[(size_t)b * H + tid + 128]);
    }
    __syncthreads();
    if (tid < 128) {
        float mean = a.eob[tid], lv = a.eob[Z + tid];
        for (int k = 0; k < 2 * H; k++) {
            float h = smem[k];
            mean += h * a.eoW[(size_t)k * 2 * Z + tid];
            lv += h * a.eoW[(size_t)k * 2 * Z + Z + tid];
        }
        float z = mean + __expf(0.5f * lv) * a.eps[(size_t)b * Z + tid];
        a.out[OUT_ZM + (size_t)b * Z + tid] = mean;
        a.out[OUT_ZL + (size_t)b * Z + tid] = lv;
        a.zbuf[(size_t)b * Z + tid] = z;
    }
    __syncthreads();
}

DEVI void run_init_zg(const CoopArgs& a, float* smem) {
    int bid = blockIdx.x, tid = threadIdx.x;
    if (bid < 64) {
        int cc = (bid & 3) * 256 + tid;
        int b0 = (bid >> 2) * 16;
        for (int i = tid; i < 16 * Z; i += 256)
            smem[i] = a.zbuf[(size_t)(b0 + (i >> 7)) * Z + (i & 127)];
        __syncthreads();
        float acc[16];
        float bias = a.ib[cc];
#pragma unroll
        for (int bb = 0; bb < 16; bb++) acc[bb] = bias;
        for (int k = 0; k < Z; k++) {
            float wv = a.iW[(size_t)k * 1024 + cc];
#pragma unroll
            for (int bb = 0; bb < 16; bb++) acc[bb] += smem[bb * 128 + k] * wv;
        }
        for (int bb = 0; bb < 16; bb++) {
            float v = tanh_(acc[bb]);
            int b = b0 + bb;
            if (cc < D) {
                unsigned short hi = f2bf(v);
                a.hs_hi[(size_t)b * D + cc] = hi;
                a.hhi_pp[(size_t)b * D + cc] = hi;  // LOCAL decoder t=0 reads slot 0
                a.hlo_pp[(size_t)b * D + cc] = f2bf(v - bf2f(hi));
            } else {
                a.c32_d[(size_t)b * D + (cc - D)] = v;
            }
        }
    } else if (bid < 192) {
        int bid2 = bid - 64;
        int cc = (bid2 & 7) * 256 + tid;
        int b0 = (bid2 >> 3) * 16;
        for (int i = tid; i < 16 * Z; i += 256)
            smem[i] = a.zbuf[(size_t)(b0 + (i >> 7)) * Z + (i & 127)];
        __syncthreads();
        float acc[16];
        float db_c = a.db[cc];
#pragma unroll
        for (int bb = 0; bb < 16; bb++) acc[bb] = db_c;
        for (int k = 0; k < Z; k++) {
            float wv = a.dWx[(size_t)(5 + k) * 2048 + cc];
#pragma unroll
            for (int bb = 0; bb < 16; bb++) acc[bb] += smem[bb * 128 + k] * wv;
        }
        int n = 4 * (cc & 511) + (cc >> 9);
#pragma unroll
        for (int bb = 0; bb < 16; bb++) a.zg[(size_t)(b0 + bb) * 2048 + n] = acc[bb];
    }
    __syncthreads();
}

__global__ __launch_bounds__(256, 1) void k_coop(CoopArgs a) {
    __shared__ float smem[2048];
    __shared__ float smx[2][160];
    __shared__ int s_info[2];
    __shared__ __align__(16) char wraw[131072];  // weight slice: hi @0, lo @65536

    // --- dynamic XCD registration: groups become XCD-local BY CONSTRUCTION ---
    if (threadIdx.x == 0) {
        unsigned x;
        asm volatile("s_getreg_b32 %0, hwreg(HW_REG_XCC_ID)" : "=s"(x));
        x &= 7;
        s_info[0] = (int)x;
        s_info[1] = (int)atomicAdd(a.reg_cnt + x * 32, 1u);  // device-scope
    }
    __syncthreads();
    int xcd = s_info[0], slot = s_info[1];
    cg::this_grid().sync();
    // grid-uniform verdict: every XCD must host exactly 32 of the 256 blocks
    bool local = (slot < 32);
#pragma unroll
    for (int i = 0; i < 8; i++) local = local && (a.reg_cnt[i * 32] == 32u);

    if (local) {
        // encoder: 2 groups per XCD (16 blocks each): dir = upper/lower slot half
        run_encoder<true>(a, smx, wraw, slot >> 4, xcd, slot & 15);
    } else {
        int bid = blockIdx.x;
        run_encoder<false>(a, smx, wraw, bid >> 7, (bid >> 4) & 7, bid & 15);
    }
    cg::this_grid().sync();
    run_encout(a, smem);
    cg::this_grid().sync();
    run_init_zg(a, smem);
    cg::this_grid().sync();
    if (local) {
        // decoder: 1 group per XCD (all 32 blocks)
        run_decoder<true>(a, smx, wraw, xcd, slot);
    } else {
        run_decoder<false>(a, smx, wraw, blockIdx.x >> 5, blockIdx.x & 31);
    }
}

// ---------------- mix GEMM ----------------
__global__ __launch_bounds__(256) void k_mix(const unsigned short* __restrict__ hs,
                                             const unsigned short* __restrict__ mixwt,
                                             const float* __restrict__ mb, float* __restrict__ dout) {
    int tid = threadIdx.x, wave = tid >> 6, lane = tid & 63, q = lane >> 4, r = lane & 15;
    int m0 = blockIdx.y * 64 + (wave >> 1) * 32;
    int n0 = blockIdx.x * 64 + (wave & 1) * 32;
    const unsigned short* A = hs + (size_t)B * D;  // ring slots 1..T
    f32x4 acc[2][2];
#pragma unroll
    for (int mi = 0; mi < 2; mi++)
#pragma unroll
        for (int ni = 0; ni < 2; ni++) acc[mi][ni] = {0.f, 0.f, 0.f, 0.f};
#pragma unroll 4
    for (int kk = 0; kk < D; kk += 32) {
        int kb = kk + q * 8;
        short8 a0 = *(const short8*)(A + (size_t)(m0 + r) * D + kb);
        short8 a1 = *(const short8*)(A + (size_t)(m0 + 16 + r) * D + kb);
        short8 b0 = *(const short8*)(mixwt + (size_t)(n0 + r) * D + kb);
        short8 b1 = *(const short8*)(mixwt + (size_t)(n0 + 16 + r) * D + kb);
        acc[0][0] = __builtin_amdgcn_mfma_f32_16x16x32_bf16(a0, b0, acc[0][0], 0, 0, 0);
        acc[0][1] = __builtin_amdgcn_mfma_f32_16x16x32_bf16(a0, b1, acc[0][1], 0, 0, 0);
        acc[1][0] = __builtin_amdgcn_mfma_f32_16x16x32_bf16(a1, b0, acc[1][0], 0, 0, 0);
        acc[1][1] = __builtin_amdgcn_mfma_f32_16x16x32_bf16(a1, b1, acc[1][1], 0, 0, 0);
    }
#pragma unroll
    for (int ni = 0; ni < 2; ni++) {
        int ncol = n0 + ni * 16 + r;
        if (ncol < P) {
            float bias = mb[ncol];
#pragma unroll
            for (int mi = 0; mi < 2; mi++) {
#pragma unroll
                for (int rr = 0; rr < 4; rr++) {
                    int m = m0 + mi * 16 + q * 4 + rr;
                    int b = m & 255, t = m >> 8;
                    dout[((size_t)b * T + t) * P + ncol] = acc[mi][ni][rr] + bias;
                }
            }
        }
    }
}

// ---------------- per-row epilogue ----------------
__global__ void k_post(float* __restrict__ dout) {
    __shared__ float row[P];
    int rid = blockIdx.x;
    int tid = threadIdx.x;
    float* base = dout + (size_t)rid * P;
    float v = 0.f;
    if (tid < P) { v = base[tid]; row[tid] = v; }
    __syncthreads();
    if (tid < P) {
        float o;
        if (tid < KMIX) {
            float mx = row[0];
            for (int i = 1; i < KMIX; i++) mx = fmaxf(mx, row[i]);
            float sm = 0.f;
            for (int i = 0; i < KMIX; i++) sm += __expf(row[i] - mx);
            o = __expf(v - mx) / sm;
        } else if (tid < 3 * KMIX) o = v;
        else if (tid < 5 * KMIX) o = __expf(v);
        else if (tid < 6 * KMIX) o = tanh_(v);
        else o = v;
        base[tid] = o;
    }
}

extern "C" void kernel_launch(void* const* d_in, const int* in_sizes, int n_in,
                              void* d_out, int out_size, void* d_ws, size_t ws_size,
                              hipStream_t stream) {
    const float* data = (const float*)d_in[0];
    const float* eps  = (const float*)d_in[1];
    const float* eWxf = (const float*)d_in[2];
    const float* eWhf = (const float*)d_in[3];
    const float* ebf  = (const float*)d_in[4];
    const float* eWxb = (const float*)d_in[5];
    const float* eWhb = (const float*)d_in[6];
    const float* ebb  = (const float*)d_in[7];
    const float* eoW  = (const float*)d_in[8];
    const float* eob  = (const float*)d_in[9];
    const float* iW   = (const float*)d_in[10];
    const float* ib   = (const float*)d_in[11];
    const float* dWx  = (const float*)d_in[12];
    const float* dWh  = (const float*)d_in[13];
    const float* db   = (const float*)d_in[14];
    const float* mW   = (const float*)d_in[15];
    const float* mb   = (const float*)d_in[16];
    float* out = (float*)d_out;

    char* base = (char*)d_ws;
    size_t off = 0;
    auto alloc = [&](size_t bytes) -> char* {
        off = (off + 255) & ~(size_t)255;
        char* p = base + off;
        off += bytes;
        return p;
    };
    unsigned short* whd_hi = (unsigned short*)alloc((size_t)2048 * 512 * 2);
    unsigned short* whd_lo = (unsigned short*)alloc((size_t)2048 * 512 * 2);
    unsigned short* whf_hi = (unsigned short*)alloc((size_t)1024 * 256 * 2);
    unsigned short* whf_lo = (unsigned short*)alloc((size_t)1024 * 256 * 2);
    unsigned short* whb_hi = (unsigned short*)alloc((size_t)1024 * 256 * 2);
    unsigned short* whb_lo = (unsigned short*)alloc((size_t)1024 * 256 * 2);
    unsigned short* mixwt  = (unsigned short*)alloc((size_t)128 * 512 * 2);
    float* wxp_dec = (float*)alloc((size_t)5 * 2048 * 4);
    float* wxp_ef  = (float*)alloc((size_t)5 * 1024 * 4);
    float* wxp_eb  = (float*)alloc((size_t)5 * 1024 * 4);
    float* bp_ef   = (float*)alloc((size_t)1024 * 4);
    float* bp_eb   = (float*)alloc((size_t)1024 * 4);
    unsigned short* hf_hi = (unsigned short*)alloc((size_t)2 * B * H * 2);
    unsigned short* hf_lo = (unsigned short*)alloc((size_t)2 * B * H * 2);
    unsigned short* hb_hi = (unsigned short*)alloc((size_t)2 * B * H * 2);
    unsigned short* hb_lo = (unsigned short*)alloc((size_t)2 * B * H * 2);
    float* c32_d  = (float*)alloc((size_t)B * D * 4);
    unsigned short* hs_hi = (unsigned short*)alloc((size_t)(T + 1) * B * D * 2);
    unsigned short* hhi_pp = (unsigned short*)alloc((size_t)2 * B * D * 2);
    unsigned short* hlo_pp = (unsigned short*)alloc((size_t)2 * B * D * 2);
    float* zbuf = (float*)alloc((size_t)B * Z * 4);
    float* zg   = (float*)alloc((size_t)B * 2048 * 4);
    unsigned* flags = (unsigned*)alloc((size_t)24 * 1024 * 4);
    unsigned* go    = (unsigned*)alloc((size_t)24 * 32 * 4);
    unsigned* ctrs  = (unsigned*)alloc((size_t)24 * 32 * 4);
    unsigned* reg_cnt = (unsigned*)alloc((size_t)256 * 4);
    (void)ws_size; (void)in_sizes; (void)n_in; (void)out_size;

    k_zero<<<256, 256, 0, stream>>>(hf_hi, hb_hi, hf_lo, hb_lo, flags, go, ctrs, reg_cnt);
    k_pack_whT<512><<<dim3(64, 16), dim3(32, 8), 0, stream>>>(dWh, whd_hi, whd_lo);
    k_pack_whT<256><<<dim3(32, 8), dim3(32, 8), 0, stream>>>(eWhf, whf_hi, whf_lo);
    k_pack_whT<256><<<dim3(32, 8), dim3(32, 8), 0, stream>>>(eWhb, whb_hi, whb_lo);
    k_pack_mix<<<256, 256, 0, stream>>>(mW, mixwt);
    k_pack_cols<<<40, 256, 0, stream>>>(dWx, wxp_dec, 512, 2048);
    k_pack_cols<<<20, 256, 0, stream>>>(eWxf, wxp_ef, 256, 1024);
    k_pack_cols<<<20, 256, 0, stream>>>(eWxb, wxp_eb, 256, 1024);
    k_pack_cols<<<4, 256, 0, stream>>>(ebf, bp_ef, 256, 1024);
    k_pack_cols<<<4, 256, 0, stream>>>(ebb, bp_eb, 256, 1024);

    CoopArgs ca;
    ca.data = data; ca.eps = eps;
    ca.whf_hi = whf_hi; ca.whf_lo = whf_lo; ca.whb_hi = whb_hi; ca.whb_lo = whb_lo;
    ca.whd_hi = whd_hi; ca.whd_lo = whd_lo;
    ca.wxp_ef = wxp_ef; ca.wxp_eb = wxp_eb; ca.wxp_dec = wxp_dec;
    ca.bp_ef = bp_ef; ca.bp_eb = bp_eb;
    ca.eoW = eoW; ca.eob = eob; ca.iW = iW; ca.ib = ib; ca.dWx = dWx; ca.db = db;
    ca.hf_hi = hf_hi; ca.hf_lo = hf_lo; ca.hb_hi = hb_hi; ca.hb_lo = hb_lo;
    ca.c32_d = c32_d;
    ca.hs_hi = hs_hi; ca.hhi_pp = hhi_pp; ca.hlo_pp = hlo_pp;
    ca.zbuf = zbuf; ca.zg = zg; ca.out = out;
    ca.flags = flags; ca.go = go; ca.ctrs = ctrs; ca.reg_cnt = reg_cnt;

    void* kp[] = { &ca };
    hipLaunchCooperativeKernel((void*)k_coop, dim3(256), dim3(256), kp, 0, stream);

    k_mix<<<dim3(2, 1000), 256, 0, stream>>>(hs_hi, mixwt, mb, out);
    k_post<<<64000, 128, 0, stream>>>(out);
}

// Round 10
// 4052.895 us; speedup vs baseline: 1.4311x; 1.2932x over previous
//
#include <hip/hip_runtime.h>
#include <hip/hip_cooperative_groups.h>

namespace cg = cooperative_groups;

typedef __attribute__((ext_vector_type(8))) short short8;
typedef __attribute__((ext_vector_type(4))) float f32x4;

static constexpr int B = 256, T = 250, Z = 128, H = 256, D = 512, KMIX = 20, P = 123;
static constexpr int PARAMS_N = B * T * P;
static constexpr int OUT_ZM = PARAMS_N;
static constexpr int OUT_ZL = PARAMS_N + B * Z;

#define DEVI static __device__ __forceinline__

DEVI unsigned short f2bf(float f) {
    unsigned int u = __float_as_uint(f);
    u += 0x7fffu + ((u >> 16) & 1u);
    return (unsigned short)(u >> 16);
}
DEVI float bf2f(unsigned short s) { return __uint_as_float(((unsigned int)s) << 16); }
DEVI float sigm(float x) { return 1.0f / (1.0f + __expf(-x)); }
DEVI float tanh_(float x) {
    x = fminf(fmaxf(x, -15.0f), 15.0f);
    float e = __expf(2.0f * x);
    return (e - 1.0f) / (e + 1.0f);
}

// static-index 4-way select (3 cndmask) — avoids runtime vector indexing (scratch)
DEVI float sel4(f32x4 v, int k) {
    float a = (k & 1) ? v[1] : v[0];
    float b = (k & 1) ? v[3] : v[2];
    return (k & 2) ? b : a;
}

// L2-executed atomic fetch_add (r7-proven correct). sc0 = return old value.
DEVI unsigned l2_fetch_add(unsigned* p, unsigned val) {
    unsigned old;
    asm volatile("global_atomic_add %0, %1, %2, off sc0\n\ts_waitcnt vmcnt(0)"
                 : "=v"(old)
                 : "v"(p), "v"(val)
                 : "memory");
    return old;
}

// ---------------- zero-init (ws is poisoned 0xAA every replay) ----------------
__global__ void k_zero(unsigned short* h1, unsigned short* h2,
                       unsigned short* h1l, unsigned short* h2l,
                       unsigned* flags, unsigned* go, unsigned* ctrs, unsigned* reg_cnt) {
    int i = blockIdx.x * 256 + threadIdx.x;  // 65536 = B*H
    h1[i] = 0; h2[i] = 0; h1l[i] = 0; h2l[i] = 0;
    if (i < 24 * 1024) flags[i] = 0;  // 24 groups x 32 blocks x 32 uints (fallback)
    if (i < 24 * 32) go[i] = 0;       // 24 groups x 1 line (fallback)
    if (i < 24 * 32) ctrs[i] = 0;     // 24 groups x 1 line (LOCAL L2 counters)
    if (i < 256) reg_cnt[i] = 0;      // 8 XCDs x 32 uints
}

// ---------------- weight packing ----------------
// Wh [K=HID][4*HID] fp32 -> hi/lo [4*HID][HID] bf16, rows packed n = 4*d + g
template <int HID>
__global__ void k_pack_whT(const float* __restrict__ Wh, unsigned short* __restrict__ ohi,
                           unsigned short* __restrict__ olo) {
    constexpr int N4 = 4 * HID;
    __shared__ float tile[32][33];
    int c0 = blockIdx.x * 32, k0 = blockIdx.y * 32;
    int tx = threadIdx.x, ty = threadIdx.y;
#pragma unroll
    for (int ii = 0; ii < 4; ii++)
        tile[ty + 8 * ii][tx] = Wh[(size_t)(k0 + ty + 8 * ii) * N4 + c0 + tx];
    __syncthreads();
#pragma unroll
    for (int ii = 0; ii < 4; ii++) {
        int j = ty + 8 * ii;
        int c = c0 + j;
        int g = c / HID, d = c % HID;
        float w = tile[tx][j];
        unsigned short hi = f2bf(w);
        unsigned short lo = f2bf(w - bf2f(hi));
        size_t o = (size_t)(4 * d + g) * HID + k0 + tx;
        ohi[o] = hi;
        olo[o] = lo;
    }
}

// mix_W [512][123] fp32 -> [128][512] bf16 (zero padded cols >=123)
__global__ void k_pack_mix(const float* __restrict__ W, unsigned short* __restrict__ out) {
    int idx = blockIdx.x * 256 + threadIdx.x;  // 128*512
    int n = idx >> 9, k = idx & 511;
    out[idx] = (n < P) ? f2bf(W[(size_t)k * P + n]) : (unsigned short)0;
}

// fp32 column permutation into packed gate order
__global__ void k_pack_cols(const float* __restrict__ in, float* __restrict__ out, int HID, int N4) {
    int idx = blockIdx.x * 256 + threadIdx.x;
    int row = idx / N4, n = idx % N4;
    out[idx] = in[(size_t)row * N4 + (n & 3) * HID + (n >> 2)];
}

// ---------------- cooperative persistent kernel ----------------
struct CoopArgs {
    const float* data;
    const float* eps;
    const unsigned short *whf_hi, *whf_lo, *whb_hi, *whb_lo, *whd_hi, *whd_lo;
    const float *wxp_ef, *wxp_eb, *wxp_dec, *bp_ef, *bp_eb;
    const float *eoW, *eob, *iW, *ib, *dWx, *db;
    unsigned short *hf_hi, *hf_lo, *hb_hi, *hb_lo;  // [2][B][H] ping-pong
    float* c32_d;
    unsigned short* hs_hi;   // [T+1][B][D] ring (k_mix input; LOCAL: written OFF the critical path)
    unsigned short* hhi_pp;  // [2][B][D] hi ping-pong (LOCAL decoder recurrence reads this, L2-hot)
    unsigned short* hlo_pp;  // [2][B][D] lo ping-pong
    float *zbuf, *zg;
    float* out;
    unsigned* flags;    // [24 groups][32 blocks][32 uints] (fallback arrivals)
    unsigned* go;       // [24 groups][32 uints] (fallback broadcast)
    unsigned* ctrs;     // [24 groups][32 uints] cumulative L2 arrival counters (LOCAL)
    unsigned* reg_cnt;  // [8 XCDs][32 uints] dynamic placement registration
};

// Group barrier (encoder LOCAL + all fallback). r7-proven.
template <bool LOCAL>
DEVI void group_barrier(unsigned* flags, unsigned* go, unsigned* ctrs, int grp, int myblk,
                        int nblk, unsigned stamp) {
    __syncthreads();
    int tid = threadIdx.x;
    if constexpr (LOCAL) {
        if (tid == 0) {
            unsigned* cp = ctrs + (size_t)grp * 32;
            unsigned target = (unsigned)nblk * stamp;
            unsigned v = l2_fetch_add(cp, 1u) + 1u;
            while (v < target) {
                __builtin_amdgcn_s_sleep(1);
                v = l2_fetch_add(cp, 0u);
            }
        }
        __syncthreads();
        asm volatile("buffer_inv sc0" ::: "memory");  // acquire: L1 inv; L2 holds fresh h
    } else {
        unsigned* gf = flags + (size_t)grp * 1024;
        if (tid == 0)
            __hip_atomic_store(gf + myblk * 32, stamp, __ATOMIC_RELAXED, __HIP_MEMORY_SCOPE_AGENT);
        if (myblk == 0 && tid < 64) {
            for (;;) {
                unsigned v = (tid < nblk)
                    ? __hip_atomic_load(gf + tid * 32, __ATOMIC_RELAXED, __HIP_MEMORY_SCOPE_AGENT)
                    : stamp;
                if (__all(v >= stamp)) break;
                __builtin_amdgcn_s_sleep(1);
            }
            if (tid == 0)
                __hip_atomic_store(go + grp * 32, stamp, __ATOMIC_RELAXED, __HIP_MEMORY_SCOPE_AGENT);
        }
        if (tid == 0) {
            while (__hip_atomic_load(go + grp * 32, __ATOMIC_RELAXED, __HIP_MEMORY_SCOPE_AGENT) < stamp)
                __builtin_amdgcn_s_sleep(1);
            __builtin_amdgcn_fence(__ATOMIC_ACQUIRE, "agent");
        }
        __syncthreads();
    }
}

// DE-REDUNDANT EPILOGUE (r8 post-mortem): VALUBusy=20% => ~2.1us/step of VALU
// work under a DVFS-depressed clock; the old epilogue computed every (c,h)
// update 4x (all 4 gate-quad lanes redundantly). New: lane with gate-index g
// owns output row q*4+g (per mi). It builds 4 FULL gate values w[k] for quad
// row (g^k) — same FMA count — and butterflies them: shfl_xor(w[k],k) delivers
// gate (g^k) of the lane's OWN row. Receive permutation == old lstm_quad table.
// LSTM transcendental blocks/thread: 40 -> 10; shfl: 32 -> 8; one store/lane/mi.
// Gate-value expression order preserved => numerically identical h.
// (r9: bench infra failed twice — container error, no kernel data. Diff vs r8
// re-audited: sync structure untouched, shuffle algebra + store coverage
// verified bijective & numerically identical. Resubmitting unchanged.)

template <bool LOCAL>
DEVI void run_encoder(const CoopArgs& a, float (*smx)[160], char* wraw, int dir, int mb, int nb) {
    int tid = threadIdx.x, w = tid >> 6, lane = tid & 63, q = lane >> 4, r = lane & 15;
    int m0 = mb * 32;
    const unsigned short* __restrict__ whi = dir ? a.whb_hi : a.whf_hi;
    const unsigned short* __restrict__ wlo = dir ? a.whb_lo : a.whf_lo;
    const float* __restrict__ wxp = dir ? a.wxp_eb : a.wxp_ef;
    const float* __restrict__ bp = dir ? a.bp_eb : a.bp_ef;
    unsigned short* __restrict__ hhi = dir ? a.hb_hi : a.hf_hi;
    unsigned short* __restrict__ hlo = dir ? a.hb_lo : a.hf_lo;
    int grp = dir * 8 + mb;
    int c0 = nb * 64;

    int c = c0 + w * 16 + r;
    int g = r & 3, d = c >> 2;
    int q4 = q * 4;
    size_t d_even = (size_t)(d & ~1);

    // stage weight slice into LDS (hi @0, lo @+65536), swizzled (r5-proven)
#pragma unroll
    for (int it = 0; it < 8; it++) {
        int m = it * 256 + tid;
        int row = m >> 5, ch = m & 31;
        int dst = row * 512 + ((ch * 16) ^ ((row & 7) << 4));
        *(short8*)(wraw + dst) = *(const short8*)(whi + (size_t)(c0 + row) * H + ch * 8);
        *(short8*)(wraw + 65536 + dst) = *(const short8*)(wlo + (size_t)(c0 + row) * H + ch * 8);
    }

    float wx0 = wxp[0 * 1024 + c], wx1 = wxp[1 * 1024 + c], wx2 = wxp[2 * 1024 + c];
    float wx3 = wxp[3 * 1024 + c], wx4 = wxp[4 * 1024 + c];
    float bias = bp[c];
    float creg[2] = {0.f, 0.f};  // one owned (row,d) per mi

    // stage x(t=0) into LDS buf 0
    {
        int tt0 = dir ? 250 : 1;
        if (tid < 32) {
            const float* p = a.data + (size_t)(m0 + tid) * (5 * (T + 1)) + (size_t)tt0 * 5;
#pragma unroll
            for (int j = 0; j < 5; j++) smx[0][tid * 5 + j] = p[j];
        }
    }
    __syncthreads();

    int crow = w * 16 + r;
    const char* pH = wraw + crow * 512;
    const char* pL = wraw + 65536 + crow * 512;
    int sw = (crow & 7) << 4;
    int q16 = q * 16;

    for (int t = 0; t < T; t++) {
        int pi = t & 1;
        const unsigned short* __restrict__ hph = hhi + (size_t)pi * B * H;
        const unsigned short* __restrict__ hpl = hlo + (size_t)pi * B * H;
        f32x4 acc0 = {0.f, 0.f, 0.f, 0.f}, acc1 = {0.f, 0.f, 0.f, 0.f};
#pragma unroll
        for (int ki = 0; ki < 8; ki++) {
            int kb = ki * 32 + q * 8;
            short8 bh = *(const short8*)(pH + ((ki * 64 + q16) ^ sw));
            short8 bl = *(const short8*)(pL + ((ki * 64 + q16) ^ sw));
            short8 a0h = *(const short8*)(hph + (size_t)(m0 + r) * H + kb);
            short8 a1h = *(const short8*)(hph + (size_t)(m0 + 16 + r) * H + kb);
            short8 a0l = *(const short8*)(hpl + (size_t)(m0 + r) * H + kb);
            short8 a1l = *(const short8*)(hpl + (size_t)(m0 + 16 + r) * H + kb);
            acc0 = __builtin_amdgcn_mfma_f32_16x16x32_bf16(a0h, bh, acc0, 0, 0, 0);
            acc1 = __builtin_amdgcn_mfma_f32_16x16x32_bf16(a1h, bh, acc1, 0, 0, 0);
            acc0 = __builtin_amdgcn_mfma_f32_16x16x32_bf16(a0l, bh, acc0, 0, 0, 0);
            acc1 = __builtin_amdgcn_mfma_f32_16x16x32_bf16(a1l, bh, acc1, 0, 0, 0);
            acc0 = __builtin_amdgcn_mfma_f32_16x16x32_bf16(a0h, bl, acc0, 0, 0, 0);
            acc1 = __builtin_amdgcn_mfma_f32_16x16x32_bf16(a1h, bl, acc1, 0, 0, 0);
        }
        // prefetch x(t+1) into the other LDS buffer (overlaps epilogue)
        if (t + 1 < T && tid < 32) {
            int ttn = dir ? (249 - t) : (2 + t);
            const float* p = a.data + (size_t)(m0 + tid) * (5 * (T + 1)) + (size_t)ttn * 5;
#pragma unroll
            for (int j = 0; j < 5; j++) smx[(t + 1) & 1][tid * 5 + j] = p[j];
        }
        unsigned short* __restrict__ hnh = hhi + (size_t)(1 - pi) * B * H;
        unsigned short* __restrict__ hnl = hlo + (size_t)(1 - pi) * B * H;
        const float* xb = smx[t & 1];
#pragma unroll
        for (int mi = 0; mi < 2; mi++) {
            f32x4 acc = mi ? acc1 : acc0;
            float wk[4];
#pragma unroll
            for (int k = 0; k < 4; k++) {
                int rr = g ^ k;
                int brow = mi * 16 + q4 + rr;
                wk[k] = sel4(acc, rr) + bias + xb[brow * 5 + 0] * wx0 + xb[brow * 5 + 1] * wx1 +
                        xb[brow * 5 + 2] * wx2 + xb[brow * 5 + 3] * wx3 + xb[brow * 5 + 4] * wx4;
            }
            float u1 = __shfl_xor(wk[1], 1, 64);
            float u2 = __shfl_xor(wk[2], 2, 64);
            float u3 = __shfl_xor(wk[3], 3, 64);
            float gi, gf, gg, go_;
            if (g == 0)      { gi = wk[0]; gf = u1;    gg = u2;    go_ = u3;    }
            else if (g == 1) { gi = u1;    gf = wk[0]; gg = u3;    go_ = u2;    }
            else if (g == 2) { gi = u2;    gf = u3;    gg = wk[0]; go_ = u1;    }
            else             { gi = u3;    gf = u2;    gg = u1;    go_ = wk[0]; }
            float cnew = sigm(gf) * creg[mi] + sigm(gi) * tanh_(gg);
            creg[mi] = cnew;
            float h = sigm(go_) * tanh_(cnew);
            float hp = __shfl_xor(h, 4, 64);  // partner: d ^ 1, same row
            size_t o = (size_t)(m0 + mi * 16 + q4 + g) * H + d_even;
            if ((r & 4) == 0) {
                unsigned pk = (unsigned)f2bf(h) | ((unsigned)f2bf(hp) << 16);
                if constexpr (LOCAL) *(unsigned*)(hnh + o) = pk;
                else __hip_atomic_store((unsigned*)(hnh + o), pk, __ATOMIC_RELAXED, __HIP_MEMORY_SCOPE_AGENT);
            } else {
                unsigned short he = f2bf(hp), ho = f2bf(h);
                unsigned pk = (unsigned)f2bf(hp - bf2f(he)) | ((unsigned)f2bf(h - bf2f(ho)) << 16);
                if constexpr (LOCAL) *(unsigned*)(hnl + o) = pk;
                else __hip_atomic_store((unsigned*)(hnl + o), pk, __ATOMIC_RELAXED, __HIP_MEMORY_SCOPE_AGENT);
            }
        }
        group_barrier<LOCAL>(a.flags, a.go, a.ctrs, grp, nb, 16, (unsigned)(t + 1));
    }
}

template <bool LOCAL>
DEVI void run_decoder(const CoopArgs& a, float (*smx)[160], char* wraw, int mb, int nb) {
    int tid = threadIdx.x, w = tid >> 6, lane = tid & 63, q = lane >> 4, r = lane & 15;
    int m0 = mb * 32;
    int grp = 16 + mb;
    int c0 = nb * 64;

    int c = c0 + w * 16 + r;
    int g = r & 3, d = c >> 2;
    int q4 = q * 4;
    size_t d_even = (size_t)(d & ~1);

    // stage weight slice into LDS (hi @0, lo @+65536), swizzled (r5-proven)
#pragma unroll
    for (int it = 0; it < 16; it++) {
        int m = it * 256 + tid;
        int row = m >> 6, ch = m & 63;
        int dst = row * 1024 + ((ch * 16) ^ ((row & 7) << 4));
        *(short8*)(wraw + dst) = *(const short8*)(a.whd_hi + (size_t)(c0 + row) * D + ch * 8);
        *(short8*)(wraw + 65536 + dst) = *(const short8*)(a.whd_lo + (size_t)(c0 + row) * D + ch * 8);
    }

    float wx0 = a.wxp_dec[0 * 2048 + c], wx1 = a.wxp_dec[1 * 2048 + c], wx2 = a.wxp_dec[2 * 2048 + c];
    float wx3 = a.wxp_dec[3 * 2048 + c], wx4 = a.wxp_dec[4 * 2048 + c];
    f32x4 zgcv[2];
    float creg[2];
#pragma unroll
    for (int mi = 0; mi < 2; mi++) {
#pragma unroll
        for (int rr = 0; rr < 4; rr++)
            zgcv[mi][rr] = a.zg[(size_t)(m0 + mi * 16 + q4 + rr) * 2048 + c];
        creg[mi] = a.c32_d[(size_t)(m0 + mi * 16 + q4 + g) * D + d];
    }

    if (tid < 32) {
        const float* p = a.data + (size_t)(m0 + tid) * (5 * (T + 1));
#pragma unroll
        for (int j = 0; j < 5; j++) smx[0][tid * 5 + j] = p[j];
    }
    __syncthreads();

    int crow = w * 16 + r;
    const char* pH = wraw + crow * 1024;
    const char* pL = wraw + 65536 + crow * 1024;
    int sw = (crow & 7) << 4;
    int q16 = q * 16;

    for (int t = 0; t < T; t++) {
        int pi = t & 1;
        // r8-proven: recurrence reads L2-hot ping-pong (LOCAL); ring written off-path
        const unsigned short* __restrict__ hph =
            LOCAL ? (a.hhi_pp + (size_t)pi * B * D) : (a.hs_hi + (size_t)t * B * D);
        const unsigned short* __restrict__ hpl = a.hlo_pp + (size_t)pi * B * D;
        f32x4 acc0 = {0.f, 0.f, 0.f, 0.f}, acc1 = {0.f, 0.f, 0.f, 0.f};
#pragma unroll
        for (int ki = 0; ki < 16; ki++) {
            int kb = ki * 32 + q * 8;
            short8 bh = *(const short8*)(pH + ((ki * 64 + q16) ^ sw));
            short8 bl = *(const short8*)(pL + ((ki * 64 + q16) ^ sw));
            short8 a0h = *(const short8*)(hph + (size_t)(m0 + r) * D + kb);
            short8 a1h = *(const short8*)(hph + (size_t)(m0 + 16 + r) * D + kb);
            short8 a0l = *(const short8*)(hpl + (size_t)(m0 + r) * D + kb);
            short8 a1l = *(const short8*)(hpl + (size_t)(m0 + 16 + r) * D + kb);
            acc0 = __builtin_amdgcn_mfma_f32_16x16x32_bf16(a0h, bh, acc0, 0, 0, 0);
            acc1 = __builtin_amdgcn_mfma_f32_16x16x32_bf16(a1h, bh, acc1, 0, 0, 0);
            acc0 = __builtin_amdgcn_mfma_f32_16x16x32_bf16(a0l, bh, acc0, 0, 0, 0);
            acc1 = __builtin_amdgcn_mfma_f32_16x16x32_bf16(a1l, bh, acc1, 0, 0, 0);
            acc0 = __builtin_amdgcn_mfma_f32_16x16x32_bf16(a0h, bl, acc0, 0, 0, 0);
            acc1 = __builtin_amdgcn_mfma_f32_16x16x32_bf16(a1h, bl, acc1, 0, 0, 0);
        }
        if (t + 1 < T && tid < 32) {
            const float* p = a.data + (size_t)(m0 + tid) * (5 * (T + 1)) + (size_t)(t + 1) * 5;
#pragma unroll
            for (int j = 0; j < 5; j++) smx[(t + 1) & 1][tid * 5 + j] = p[j];
        }
        const float* xb = smx[t & 1];
        unsigned ringw[2];  // hi words (even-d lanes), one per mi
        unsigned short* __restrict__ hnh =
            LOCAL ? (a.hhi_pp + (size_t)(1 - pi) * B * D) : (a.hs_hi + (size_t)(t + 1) * B * D);
        unsigned short* __restrict__ hnl = a.hlo_pp + (size_t)(1 - pi) * B * D;
#pragma unroll
        for (int mi = 0; mi < 2; mi++) {
            f32x4 acc = mi ? acc1 : acc0;
            float wk[4];
#pragma unroll
            for (int k = 0; k < 4; k++) {
                int rr = g ^ k;
                int brow = mi * 16 + q4 + rr;
                wk[k] = sel4(acc, rr) + sel4(zgcv[mi], rr) + xb[brow * 5 + 0] * wx0 +
                        xb[brow * 5 + 1] * wx1 + xb[brow * 5 + 2] * wx2 +
                        xb[brow * 5 + 3] * wx3 + xb[brow * 5 + 4] * wx4;
            }
            float u1 = __shfl_xor(wk[1], 1, 64);
            float u2 = __shfl_xor(wk[2], 2, 64);
            float u3 = __shfl_xor(wk[3], 3, 64);
            float gi, gf, gg, go_;
            if (g == 0)      { gi = wk[0]; gf = u1;    gg = u2;    go_ = u3;    }
            else if (g == 1) { gi = u1;    gf = wk[0]; gg = u3;    go_ = u2;    }
            else if (g == 2) { gi = u2;    gf = u3;    gg = wk[0]; go_ = u1;    }
            else             { gi = u3;    gf = u2;    gg = u1;    go_ = wk[0]; }
            float cnew = sigm(gf) * creg[mi] + sigm(gi) * tanh_(gg);
            creg[mi] = cnew;
            float h = sigm(go_) * tanh_(cnew);
            float hp = __shfl_xor(h, 4, 64);  // partner: d ^ 1, same row
            size_t o = (size_t)(m0 + mi * 16 + q4 + g) * D + d_even;
            if ((r & 4) == 0) {
                unsigned pk = (unsigned)f2bf(h) | ((unsigned)f2bf(hp) << 16);
                ringw[mi] = pk;
                if constexpr (LOCAL) *(unsigned*)(hnh + o) = pk;
                else __hip_atomic_store((unsigned*)(hnh + o), pk, __ATOMIC_RELAXED, __HIP_MEMORY_SCOPE_AGENT);
            } else {
                unsigned short he = f2bf(hp), ho = f2bf(h);
                unsigned pk = (unsigned)f2bf(hp - bf2f(he)) | ((unsigned)f2bf(h - bf2f(ho)) << 16);
                if constexpr (LOCAL) *(unsigned*)(hnl + o) = pk;
                else __hip_atomic_store((unsigned*)(hnl + o), pk, __ATOMIC_RELAXED, __HIP_MEMORY_SCOPE_AGENT);
            }
        }
        if constexpr (LOCAL) {
            // barrier with ring stores off the critical path (r8-proven):
            __syncthreads();  // drains hot ping-pong stores (+ last step's ring, long done)
            if (tid == 0) {
                unsigned* cp = a.ctrs + (size_t)grp * 32;
                unsigned target = 32u * (unsigned)(t + 1);
                unsigned v = l2_fetch_add(cp, 1u) + 1u;  // arrive (clean vmcnt)
                while (v < target) {
                    __builtin_amdgcn_s_sleep(1);
                    v = l2_fetch_add(cp, 0u);
                }
            }
            if ((r & 4) == 0) {
                unsigned short* __restrict__ ring = a.hs_hi + (size_t)(t + 1) * B * D;
                size_t o0 = (size_t)(m0 + q4 + g) * D + d_even;
                *(unsigned*)(ring + o0) = ringw[0];
                *(unsigned*)(ring + o0 + (size_t)16 * D) = ringw[1];
            }
            __builtin_amdgcn_s_barrier();  // raw: no vmcnt drain here
            asm volatile("buffer_inv sc0" ::: "memory");  // acquire: L1 inv; L2 holds fresh h
        } else {
            group_barrier<false>(a.flags, a.go, a.ctrs, grp, nb, 32, (unsigned)(t + 1));
        }
    }
}

DEVI void run_encout(const CoopArgs& a, float* smem) {
    int b = blockIdx.x, tid = threadIdx.x;
    // final encoder h is in ping-pong slot 0 (T=250 even)
    if (tid < 128) {
        smem[tid]       = bf2f(a.hf_hi[(size_t)b * H + tid])       + bf2f(a.hf_lo[(size_t)b * H + tid]);
        smem[tid + 128] = bf2f(a.hf_hi[(size_t)b * H + tid + 128]) + bf2f(a.hf_lo[(size_t)b * H + tid + 128]);
        smem[tid + 256] = bf2f(a.hb_hi[(size_t)b * H + tid])       + bf2f(a.hb_lo[(size_t)b * H + tid]);
        smem[tid + 384] = bf2f(a.hb_hi[(size_t)b * H + tid + 128]) + bf2f(a.hb_lo[(size_t)b * H + tid + 128]);
    }
    __syncthreads();
    if (tid < 128) {
        float mean = a.eob[tid], lv = a.eob[Z + tid];
        for (int k = 0; k < 2 * H; k++) {
            float h = smem[k];
            mean += h * a.eoW[(size_t)k * 2 * Z + tid];
            lv += h * a.eoW[(size_t)k * 2 * Z + Z + tid];
        }
        float z = mean + __expf(0.5f * lv) * a.eps[(size_t)b * Z + tid];
        a.out[OUT_ZM + (size_t)b * Z + tid] = mean;
        a.out[OUT_ZL + (size_t)b * Z + tid] = lv;
        a.zbuf[(size_t)b * Z + tid] = z;
    }
    __syncthreads();
}

DEVI void run_init_zg(const CoopArgs& a, float* smem) {
    int bid = blockIdx.x, tid = threadIdx.x;
    if (bid < 64) {
        int cc = (bid & 3) * 256 + tid;
        int b0 = (bid >> 2) * 16;
        for (int i = tid; i < 16 * Z; i += 256)
            smem[i] = a.zbuf[(size_t)(b0 + (i >> 7)) * Z + (i & 127)];
        __syncthreads();
        float acc[16];
        float bias = a.ib[cc];
#pragma unroll
        for (int bb = 0; bb < 16; bb++) acc[bb] = bias;
        for (int k = 0; k < Z; k++) {
            float wv = a.iW[(size_t)k * 1024 + cc];
#pragma unroll
            for (int bb = 0; bb < 16; bb++) acc[bb] += smem[bb * 128 + k] * wv;
        }
        for (int bb = 0; bb < 16; bb++) {
            float v = tanh_(acc[bb]);
            int b = b0 + bb;
            if (cc < D) {
                unsigned short hi = f2bf(v);
                a.hs_hi[(size_t)b * D + cc] = hi;
                a.hhi_pp[(size_t)b * D + cc] = hi;  // LOCAL decoder t=0 reads slot 0
                a.hlo_pp[(size_t)b * D + cc] = f2bf(v - bf2f(hi));
            } else {
                a.c32_d[(size_t)b * D + (cc - D)] = v;
            }
        }
    } else if (bid < 192) {
        int bid2 = bid - 64;
        int cc = (bid2 & 7) * 256 + tid;
        int b0 = (bid2 >> 3) * 16;
        for (int i = tid; i < 16 * Z; i += 256)
            smem[i] = a.zbuf[(size_t)(b0 + (i >> 7)) * Z + (i & 127)];
        __syncthreads();
        float acc[16];
        float db_c = a.db[cc];
#pragma unroll
        for (int bb = 0; bb < 16; bb++) acc[bb] = db_c;
        for (int k = 0; k < Z; k++) {
            float wv = a.dWx[(size_t)(5 + k) * 2048 + cc];
#pragma unroll
            for (int bb = 0; bb < 16; bb++) acc[bb] += smem[bb * 128 + k] * wv;
        }
        int n = 4 * (cc & 511) + (cc >> 9);
#pragma unroll
        for (int bb = 0; bb < 16; bb++) a.zg[(size_t)(b0 + bb) * 2048 + n] = acc[bb];
    }
    __syncthreads();
}

__global__ __launch_bounds__(256, 1) void k_coop(CoopArgs a) {
    __shared__ float smem[2048];
    __shared__ float smx[2][160];
    __shared__ int s_info[2];
    __shared__ __align__(16) char wraw[131072];  // weight slice: hi @0, lo @65536

    // --- dynamic XCD registration: groups become XCD-local BY CONSTRUCTION ---
    if (threadIdx.x == 0) {
        unsigned x;
        asm volatile("s_getreg_b32 %0, hwreg(HW_REG_XCC_ID)" : "=s"(x));
        x &= 7;
        s_info[0] = (int)x;
        s_info[1] = (int)atomicAdd(a.reg_cnt + x * 32, 1u);  // device-scope
    }
    __syncthreads();
    int xcd = s_info[0], slot = s_info[1];
    cg::this_grid().sync();
    // grid-uniform verdict: every XCD must host exactly 32 of the 256 blocks
    bool local = (slot < 32);
#pragma unroll
    for (int i = 0; i < 8; i++) local = local && (a.reg_cnt[i * 32] == 32u);

    if (local) {
        // encoder: 2 groups per XCD (16 blocks each): dir = upper/lower slot half
        run_encoder<true>(a, smx, wraw, slot >> 4, xcd, slot & 15);
    } else {
        int bid = blockIdx.x;
        run_encoder<false>(a, smx, wraw, bid >> 7, (bid >> 4) & 7, bid & 15);
    }
    cg::this_grid().sync();
    run_encout(a, smem);
    cg::this_grid().sync();
    run_init_zg(a, smem);
    cg::this_grid().sync();
    if (local) {
        // decoder: 1 group per XCD (all 32 blocks)
        run_decoder<true>(a, smx, wraw, xcd, slot);
    } else {
        run_decoder<false>(a, smx, wraw, blockIdx.x >> 5, blockIdx.x & 31);
    }
}

// ---------------- mix GEMM ----------------
__global__ __launch_bounds__(256) void k_mix(const unsigned short* __restrict__ hs,
                                             const unsigned short* __restrict__ mixwt,
                                             const float* __restrict__ mb, float* __restrict__ dout) {
    int tid = threadIdx.x, wave = tid >> 6, lane = tid & 63, q = lane >> 4, r = lane & 15;
    int m0 = blockIdx.y * 64 + (wave >> 1) * 32;
    int n0 = blockIdx.x * 64 + (wave & 1) * 32;
    const unsigned short* A = hs + (size_t)B * D;  // ring slots 1..T
    f32x4 acc[2][2];
#pragma unroll
    for (int mi = 0; mi < 2; mi++)
#pragma unroll
        for (int ni = 0; ni < 2; ni++) acc[mi][ni] = {0.f, 0.f, 0.f, 0.f};
#pragma unroll 4
    for (int kk = 0; kk < D; kk += 32) {
        int kb = kk + q * 8;
        short8 a0 = *(const short8*)(A + (size_t)(m0 + r) * D + kb);
        short8 a1 = *(const short8*)(A + (size_t)(m0 + 16 + r) * D + kb);
        short8 b0 = *(const short8*)(mixwt + (size_t)(n0 + r) * D + kb);
        short8 b1 = *(const short8*)(mixwt + (size_t)(n0 + 16 + r) * D + kb);
        acc[0][0] = __builtin_amdgcn_mfma_f32_16x16x32_bf16(a0, b0, acc[0][0], 0, 0, 0);
        acc[0][1] = __builtin_amdgcn_mfma_f32_16x16x32_bf16(a0, b1, acc[0][1], 0, 0, 0);
        acc[1][0] = __builtin_amdgcn_mfma_f32_16x16x32_bf16(a1, b0, acc[1][0], 0, 0, 0);
        acc[1][1] = __builtin_amdgcn_mfma_f32_16x16x32_bf16(a1, b1, acc[1][1], 0, 0, 0);
    }
#pragma unroll
    for (int ni = 0; ni < 2; ni++) {
        int ncol = n0 + ni * 16 + r;
        if (ncol < P) {
            float bias = mb[ncol];
#pragma unroll
            for (int mi = 0; mi < 2; mi++) {
#pragma unroll
                for (int rr = 0; rr < 4; rr++) {
                    int m = m0 + mi * 16 + q * 4 + rr;
                    int b = m & 255, t = m >> 8;
                    dout[((size_t)b * T + t) * P + ncol] = acc[mi][ni][rr] + bias;
                }
            }
        }
    }
}

// ---------------- per-row epilogue ----------------
__global__ void k_post(float* __restrict__ dout) {
    __shared__ float row[P];
    int rid = blockIdx.x;
    int tid = threadIdx.x;
    float* base = dout + (size_t)rid * P;
    float v = 0.f;
    if (tid < P) { v = base[tid]; row[tid] = v; }
    __syncthreads();
    if (tid < P) {
        float o;
        if (tid < KMIX) {
            float mx = row[0];
            for (int i = 1; i < KMIX; i++) mx = fmaxf(mx, row[i]);
            float sm = 0.f;
            for (int i = 0; i < KMIX; i++) sm += __expf(row[i] - mx);
            o = __expf(v - mx) / sm;
        } else if (tid < 3 * KMIX) o = v;
        else if (tid < 5 * KMIX) o = __expf(v);
        else if (tid < 6 * KMIX) o = tanh_(v);
        else o = v;
        base[tid] = o;
    }
}

extern "C" void kernel_launch(void* const* d_in, const int* in_sizes, int n_in,
                              void* d_out, int out_size, void* d_ws, size_t ws_size,
                              hipStream_t stream) {
    const float* data = (const float*)d_in[0];
    const float* eps  = (const float*)d_in[1];
    const float* eWxf = (const float*)d_in[2];
    const float* eWhf = (const float*)d_in[3];
    const float* ebf  = (const float*)d_in[4];
    const float* eWxb = (const float*)d_in[5];
    const float* eWhb = (const float*)d_in[6];
    const float* ebb  = (const float*)d_in[7];
    const float* eoW  = (const float*)d_in[8];
    const float* eob  = (const float*)d_in[9];
    const float* iW   = (const float*)d_in[10];
    const float* ib   = (const float*)d_in[11];
    const float* dWx  = (const float*)d_in[12];
    const float* dWh  = (const float*)d_in[13];
    const float* db   = (const float*)d_in[14];
    const float* mW   = (const float*)d_in[15];
    const float* mb   = (const float*)d_in[16];
    float* out = (float*)d_out;

    char* base = (char*)d_ws;
    size_t off = 0;
    auto alloc = [&](size_t bytes) -> char* {
        off = (off + 255) & ~(size_t)255;
        char* p = base + off;
        off += bytes;
        return p;
    };
    unsigned short* whd_hi = (unsigned short*)alloc((size_t)2048 * 512 * 2);
    unsigned short* whd_lo = (unsigned short*)alloc((size_t)2048 * 512 * 2);
    unsigned short* whf_hi = (unsigned short*)alloc((size_t)1024 * 256 * 2);
    unsigned short* whf_lo = (unsigned short*)alloc((size_t)1024 * 256 * 2);
    unsigned short* whb_hi = (unsigned short*)alloc((size_t)1024 * 256 * 2);
    unsigned short* whb_lo = (unsigned short*)alloc((size_t)1024 * 256 * 2);
    unsigned short* mixwt  = (unsigned short*)alloc((size_t)128 * 512 * 2);
    float* wxp_dec = (float*)alloc((size_t)5 * 2048 * 4);
    float* wxp_ef  = (float*)alloc((size_t)5 * 1024 * 4);
    float* wxp_eb  = (float*)alloc((size_t)5 * 1024 * 4);
    float* bp_ef   = (float*)alloc((size_t)1024 * 4);
    float* bp_eb   = (float*)alloc((size_t)1024 * 4);
    unsigned short* hf_hi = (unsigned short*)alloc((size_t)2 * B * H * 2);
    unsigned short* hf_lo = (unsigned short*)alloc((size_t)2 * B * H * 2);
    unsigned short* hb_hi = (unsigned short*)alloc((size_t)2 * B * H * 2);
    unsigned short* hb_lo = (unsigned short*)alloc((size_t)2 * B * H * 2);
    float* c32_d  = (float*)alloc((size_t)B * D * 4);
    unsigned short* hs_hi = (unsigned short*)alloc((size_t)(T + 1) * B * D * 2);
    unsigned short* hhi_pp = (unsigned short*)alloc((size_t)2 * B * D * 2);
    unsigned short* hlo_pp = (unsigned short*)alloc((size_t)2 * B * D * 2);
    float* zbuf = (float*)alloc((size_t)B * Z * 4);
    float* zg   = (float*)alloc((size_t)B * 2048 * 4);
    unsigned* flags = (unsigned*)alloc((size_t)24 * 1024 * 4);
    unsigned* go    = (unsigned*)alloc((size_t)24 * 32 * 4);
    unsigned* ctrs  = (unsigned*)alloc((size_t)24 * 32 * 4);
    unsigned* reg_cnt = (unsigned*)alloc((size_t)256 * 4);
    (void)ws_size; (void)in_sizes; (void)n_in; (void)out_size;

    k_zero<<<256, 256, 0, stream>>>(hf_hi, hb_hi, hf_lo, hb_lo, flags, go, ctrs, reg_cnt);
    k_pack_whT<512><<<dim3(64, 16), dim3(32, 8), 0, stream>>>(dWh, whd_hi, whd_lo);
    k_pack_whT<256><<<dim3(32, 8), dim3(32, 8), 0, stream>>>(eWhf, whf_hi, whf_lo);
    k_pack_whT<256><<<dim3(32, 8), dim3(32, 8), 0, stream>>>(eWhb, whb_hi, whb_lo);
    k_pack_mix<<<256, 256, 0, stream>>>(mW, mixwt);
    k_pack_cols<<<40, 256, 0, stream>>>(dWx, wxp_dec, 512, 2048);
    k_pack_cols<<<20, 256, 0, stream>>>(eWxf, wxp_ef, 256, 1024);
    k_pack_cols<<<20, 256, 0, stream>>>(eWxb, wxp_eb, 256, 1024);
    k_pack_cols<<<4, 256, 0, stream>>>(ebf, bp_ef, 256, 1024);
    k_pack_cols<<<4, 256, 0, stream>>>(ebb, bp_eb, 256, 1024);

    CoopArgs ca;
    ca.data = data; ca.eps = eps;
    ca.whf_hi = whf_hi; ca.whf_lo = whf_lo; ca.whb_hi = whb_hi; ca.whb_lo = whb_lo;
    ca.whd_hi = whd_hi; ca.whd_lo = whd_lo;
    ca.wxp_ef = wxp_ef; ca.wxp_eb = wxp_eb; ca.wxp_dec = wxp_dec;
    ca.bp_ef = bp_ef; ca.bp_eb = bp_eb;
    ca.eoW = eoW; ca.eob = eob; ca.iW = iW; ca.ib = ib; ca.dWx = dWx; ca.db = db;
    ca.hf_hi = hf_hi; ca.hf_lo = hf_lo; ca.hb_hi = hb_hi; ca.hb_lo = hb_lo;
    ca.c32_d = c32_d;
    ca.hs_hi = hs_hi; ca.hhi_pp = hhi_pp; ca.hlo_pp = hlo_pp;
    ca.zbuf = zbuf; ca.zg = zg; ca.out = out;
    ca.flags = flags; ca.go = go; ca.ctrs = ctrs; ca.reg_cnt = reg_cnt;

    void* kp[] = { &ca };
    hipLaunchCooperativeKernel((void*)k_coop, dim3(256), dim3(256), kp, 0, stream);

    k_mix<<<dim3(2, 1000), 256, 0, stream>>>(hs_hi, mixwt, mb, out);
    k_post<<<64000, 128, 0, stream>>>(out);
}